// Round 6
// baseline (677.825 us; speedup 1.0000x reference)
//
#include <hip/hip_runtime.h>
#include <hip/hip_bf16.h>

// Problem constants (match reference)
#define N_NODES  100000
#define N_EDGES  1600000
#define N_GRAPHS 2048
#define DIM      128   // IN_DIM == HIDDEN == 128

// ===========================================================================
// CSR construction: count -> 3-phase exclusive scan -> XCD-partitioned fill
// ===========================================================================
__global__ __launch_bounds__(256)
void cnt_kernel(const int* __restrict__ dst, int* __restrict__ cnt, int E)
{
    int e0 = (blockIdx.x * blockDim.x + threadIdx.x) * 4;
    if (e0 + 3 < E) {
        int4 d = *(const int4*)&dst[e0];
        atomicAdd(&cnt[d.x], 1);
        atomicAdd(&cnt[d.y], 1);
        atomicAdd(&cnt[d.z], 1);
        atomicAdd(&cnt[d.w], 1);
    } else {
        for (int e = e0; e < E; ++e) atomicAdd(&cnt[dst[e]], 1);
    }
}

#define SCAN_T     256
#define SCAN_E     4
#define SCAN_CHUNK 1024   // SCAN_T * SCAN_E
#define SCAN_NBLK  ((N_NODES + SCAN_CHUNK - 1) / SCAN_CHUNK)   // 98

__global__ __launch_bounds__(SCAN_T)
void scan1(const int* __restrict__ cnt, int* __restrict__ rp,
           int* __restrict__ bsum, int N)
{
    __shared__ int sh[SCAN_T];
    int b = blockIdx.x, t = threadIdx.x;
    int base = b * SCAN_CHUNK + t * SCAN_E;
    int v[SCAN_E];
    int s = 0;
#pragma unroll
    for (int i = 0; i < SCAN_E; ++i) {
        int idx = base + i;
        v[i] = (idx < N) ? cnt[idx] : 0;
        s += v[i];
    }
    sh[t] = s;
    __syncthreads();
    for (int off = 1; off < SCAN_T; off <<= 1) {
        int add = (t >= off) ? sh[t - off] : 0;
        __syncthreads();
        sh[t] += add;
        __syncthreads();
    }
    int excl = sh[t] - s;
    if (t == SCAN_T - 1) bsum[b] = sh[t];
    int run = excl;
#pragma unroll
    for (int i = 0; i < SCAN_E; ++i) {
        int idx = base + i;
        if (idx < N) rp[idx] = run;
        run += v[i];
    }
}

__global__ __launch_bounds__(128)
void scan2(int* __restrict__ bsum, int nb)
{
    __shared__ int sh[128];
    int t = threadIdx.x;
    int v = (t < nb) ? bsum[t] : 0;
    sh[t] = v;
    __syncthreads();
    for (int off = 1; off < 128; off <<= 1) {
        int add = (t >= off) ? sh[t - off] : 0;
        __syncthreads();
        sh[t] += add;
        __syncthreads();
    }
    if (t < nb) bsum[t] = sh[t] - v;   // exclusive
}

// Phase 3: add block offsets; emit row_ptr + cursor; also cnt -> dinv (fused)
__global__ __launch_bounds__(256)
void scan3(int* __restrict__ rp, int* __restrict__ cursor,
           const int* __restrict__ bsum, int* __restrict__ cnt, int N, int E)
{
    int i = blockIdx.x * blockDim.x + threadIdx.x;
    if (i < N) {
        int v = rp[i] + bsum[i / SCAN_CHUNK];
        rp[i] = v;
        cursor[i] = v;
        float d = (float)cnt[i] + 1.0f;
        ((float*)cnt)[i] = rsqrtf(d);   // in-place: cnt buffer becomes dinv
    }
    if (i == N) rp[N] = E;
}

// XCD-partitioned fill (round-4 win: keeps csr-line fills within one XCD L2)
#define FILL_RANGES 8
#define FILL_RSIZE  (N_NODES / FILL_RANGES)   // 12500 exact
__global__ __launch_bounds__(256)
void csr_fill(const int* __restrict__ src, const int* __restrict__ dst,
              int* __restrict__ cursor, int* __restrict__ csr, int E)
{
    const int r = blockIdx.x & (FILL_RANGES - 1);
    const int s = blockIdx.x >> 3;
    const int nslice = gridDim.x >> 3;
    const unsigned lo = (unsigned)(r * FILL_RSIZE);
    const int stride = nslice * 256 * 4;

    for (int e0 = (s * 256 + threadIdx.x) * 4; e0 < E; e0 += stride) {
        int4 d  = *(const int4*)&dst[e0];
        int4 sv = *(const int4*)&src[e0];
        if ((unsigned)(d.x - lo) < (unsigned)FILL_RSIZE) {
            int p = atomicAdd(&cursor[d.x], 1); csr[p] = sv.x;
        }
        if ((unsigned)(d.y - lo) < (unsigned)FILL_RSIZE) {
            int p = atomicAdd(&cursor[d.y], 1); csr[p] = sv.y;
        }
        if ((unsigned)(d.z - lo) < (unsigned)FILL_RSIZE) {
            int p = atomicAdd(&cursor[d.z], 1); csr[p] = sv.z;
        }
        if ((unsigned)(d.w - lo) < (unsigned)FILL_RSIZE) {
            int p = atomicAdd(&cursor[d.w], 1); csr[p] = sv.w;
        }
    }
}

// ===========================================================================
// CSR gather: Out[i] = V[i] + sum_{e in [rp[i],rp[i+1])} V[csr[e]]
// One node per 32-lane group, float4 per lane, x4 unroll. No LDS -> high
// occupancy (the memory-parallelism this latency/BW-bound kernel needs).
// ===========================================================================
__global__ __launch_bounds__(256)
void csr_gather(const int* __restrict__ rp, const int* __restrict__ csr,
                const float* __restrict__ V, float* __restrict__ Out, int N)
{
    int node = blockIdx.x * 8 + (threadIdx.x >> 5);
    int lane = threadIdx.x & 31;
    if (node >= N) return;
    int beg = rp[node];
    int end = rp[node + 1];
    const float4* V4 = (const float4*)V;
    float4 acc = V4[(size_t)node * 32 + lane];   // self term
    int e = beg;
    for (; e + 4 <= end; e += 4) {
        int s0 = csr[e + 0];
        int s1 = csr[e + 1];
        int s2 = csr[e + 2];
        int s3 = csr[e + 3];
        float4 v0 = V4[(size_t)s0 * 32 + lane];
        float4 v1 = V4[(size_t)s1 * 32 + lane];
        float4 v2 = V4[(size_t)s2 * 32 + lane];
        float4 v3 = V4[(size_t)s3 * 32 + lane];
        acc.x += v0.x + v1.x + v2.x + v3.x;
        acc.y += v0.y + v1.y + v2.y + v3.y;
        acc.z += v0.z + v1.z + v2.z + v3.z;
        acc.w += v0.w + v1.w + v2.w + v3.w;
    }
    for (; e < end; ++e) {
        int s = csr[e];
        float4 v = V4[(size_t)s * 32 + lane];
        acc.x += v.x; acc.y += v.y; acc.z += v.z; acc.w += v.w;
    }
    ((float4*)Out)[(size_t)node * 32 + lane] = acc;
}

// ===========================================================================
// Fused 3-layer MLP (compute-only; H tile LDS-resident across layers):
//   L0: H = relu(H @ w1 + b1)
//   L1: H = relu(H @ w2 + b2)
//   L2: u  = dinv[row] * (H @ w3)   -> global
// MB=64 rows/block, 256 threads, thread tile 4x8. LDS 49.2 KB -> 3 blocks/CU
// (fine: compute-bound). Eliminates 204 MB of inter-GEMM HBM round-trips.
// ===========================================================================
#define MB    64
#define HPAD  129

__global__ __launch_bounds__(256)
void mlp3(const float* __restrict__ Hin,
          const float* __restrict__ w1, const float* __restrict__ b1,
          const float* __restrict__ w2, const float* __restrict__ b2,
          const float* __restrict__ w3, const float* __restrict__ dinv,
          float* __restrict__ u_out, int N)
{
    __shared__ float H[MB][HPAD];
    __shared__ float Ws[32][DIM];

    const int tid  = threadIdx.x;
    const int row0 = blockIdx.x * MB;

    // ---- load H tile from global (coalesced): 2048 float4, 8/thread ----
#pragma unroll
    for (int l = 0; l < 8; ++l) {
        int f  = tid + l * 256;
        int r  = f >> 5;
        int c4 = (f & 31) << 2;
        int gr = row0 + r;
        float4 v = make_float4(0.f, 0.f, 0.f, 0.f);
        if (gr < N) v = *(const float4*)&Hin[(size_t)gr * DIM + c4];
        H[r][c4 + 0] = v.x;
        H[r][c4 + 1] = v.y;
        H[r][c4 + 2] = v.z;
        H[r][c4 + 3] = v.w;
    }
    __syncthreads();

    const int tx = tid & 15;   // 16 col groups * 8 = 128
    const int ty = tid >> 4;   // 16 row groups * 4 = 64

    for (int layer = 0; layer < 3; ++layer) {
        const float* W = (layer == 0) ? w1 : (layer == 1) ? w2 : w3;
        float acc[4][8];
#pragma unroll
        for (int i = 0; i < 4; ++i)
#pragma unroll
            for (int j = 0; j < 8; ++j) acc[i][j] = 0.f;

        for (int kt = 0; kt < DIM; kt += 32) {
            // stage W[kt..kt+31][0..127] -> Ws (L2-hot after first blocks)
#pragma unroll
            for (int l = 0; l < 4; ++l) {
                int f  = tid + l * 256;
                int rr = f >> 5;
                int c4 = (f & 31) << 2;
                *(float4*)&Ws[rr][c4] = *(const float4*)&W[(size_t)(kt + rr) * DIM + c4];
            }
            __syncthreads();
#pragma unroll
            for (int kk = 0; kk < 32; ++kk) {
                float b[8];
                *(float4*)&b[0] = *(const float4*)&Ws[kk][tx * 8 + 0];
                *(float4*)&b[4] = *(const float4*)&Ws[kk][tx * 8 + 4];
                float a[4];
#pragma unroll
                for (int i = 0; i < 4; ++i) a[i] = H[ty * 4 + i][kt + kk];
#pragma unroll
                for (int i = 0; i < 4; ++i)
#pragma unroll
                    for (int j = 0; j < 8; ++j)
                        acc[i][j] = fmaf(a[i], b[j], acc[i][j]);
            }
            __syncthreads();
        }

        if (layer < 2) {
            const float* bias = (layer == 0) ? b1 : b2;
            float bv[8];
#pragma unroll
            for (int j = 0; j < 8; ++j) bv[j] = bias[tx * 8 + j];
#pragma unroll
            for (int i = 0; i < 4; ++i) {
#pragma unroll
                for (int j = 0; j < 8; ++j)
                    H[ty * 4 + i][tx * 8 + j] = fmaxf(acc[i][j] + bv[j], 0.f);
            }
            __syncthreads();
        } else {
            // u = dinv * (H @ w3), coalesced float4 x2 store
#pragma unroll
            for (int i = 0; i < 4; ++i) {
                int r = row0 + ty * 4 + i;
                if (r < N) {
                    float di = dinv[r];
                    float v[8];
#pragma unroll
                    for (int j = 0; j < 8; ++j) v[j] = di * acc[i][j];
                    *(float4*)&u_out[(size_t)r * DIM + tx * 8 + 0] = *(const float4*)&v[0];
                    *(float4*)&u_out[(size_t)r * DIM + tx * 8 + 4] = *(const float4*)&v[4];
                }
            }
        }
    }
}

// ===========================================================================
// Fused GCN gather + finalize + global_add_pool:
//   h_i = relu(dinv_i * (u_i + sum u[csr]) + b);  g[batch[i]] += h_i
// ===========================================================================
#define P2_NODES 64
__global__ __launch_bounds__(256)
void gcn_gather_pool(const int* __restrict__ rp, const int* __restrict__ csr,
                     const float* __restrict__ u, const float* __restrict__ dinv,
                     const float* __restrict__ bias, const int* __restrict__ batch,
                     float* __restrict__ g, int N)
{
    const int grp  = threadIdx.x >> 5;
    const int lane = threadIdx.x & 31;
    const int n0   = blockIdx.x * P2_NODES + grp * 8;
    const float4* V4 = (const float4*)u;

    float4 bj;
    bj.x = bias[lane * 4 + 0];
    bj.y = bias[lane * 4 + 1];
    bj.z = bias[lane * 4 + 2];
    bj.w = bias[lane * 4 + 3];

    float4 lsum = make_float4(0.f, 0.f, 0.f, 0.f);
    int prev = -1;

    for (int k = 0; k < 8; ++k) {
        int node = n0 + k;
        if (node >= N) break;
        float4 acc = V4[(size_t)node * 32 + lane];   // self term u_i
        int e = rp[node], end = rp[node + 1];
        for (; e + 4 <= end; e += 4) {
            int s0 = csr[e + 0], s1 = csr[e + 1];
            int s2 = csr[e + 2], s3 = csr[e + 3];
            float4 v0 = V4[(size_t)s0 * 32 + lane];
            float4 v1 = V4[(size_t)s1 * 32 + lane];
            float4 v2 = V4[(size_t)s2 * 32 + lane];
            float4 v3 = V4[(size_t)s3 * 32 + lane];
            acc.x += v0.x + v1.x + v2.x + v3.x;
            acc.y += v0.y + v1.y + v2.y + v3.y;
            acc.z += v0.z + v1.z + v2.z + v3.z;
            acc.w += v0.w + v1.w + v2.w + v3.w;
        }
        for (; e < end; ++e) {
            int s = csr[e];
            float4 v = V4[(size_t)s * 32 + lane];
            acc.x += v.x; acc.y += v.y; acc.z += v.z; acc.w += v.w;
        }
        float di = dinv[node];
        float4 h;
        h.x = fmaxf(fmaf(di, acc.x, bj.x), 0.f);
        h.y = fmaxf(fmaf(di, acc.y, bj.y), 0.f);
        h.z = fmaxf(fmaf(di, acc.z, bj.z), 0.f);
        h.w = fmaxf(fmaf(di, acc.w, bj.w), 0.f);

        int b = batch[node];
        if (b != prev) {
            if (prev >= 0) {
                float* gp = &g[(size_t)prev * DIM + lane * 4];
                atomicAdd(gp + 0, lsum.x);
                atomicAdd(gp + 1, lsum.y);
                atomicAdd(gp + 2, lsum.z);
                atomicAdd(gp + 3, lsum.w);
            }
            lsum = make_float4(0.f, 0.f, 0.f, 0.f);
            prev = b;
        }
        lsum.x += h.x; lsum.y += h.y; lsum.z += h.z; lsum.w += h.w;
    }
    if (prev >= 0) {
        float* gp = &g[(size_t)prev * DIM + lane * 4];
        atomicAdd(gp + 0, lsum.x);
        atomicAdd(gp + 1, lsum.y);
        atomicAdd(gp + 2, lsum.z);
        atomicAdd(gp + 3, lsum.w);
    }
}

// ===========================================================================
// Head: out[gid] = relu(g[gid] @ lin1_w + b1) @ lin2_w + b2
// ===========================================================================
__global__ __launch_bounds__(128)
void head_kernel(const float* __restrict__ g, const float* __restrict__ w1,
                 const float* __restrict__ b1, const float* __restrict__ w2,
                 const float* __restrict__ b2, float* __restrict__ out)
{
    __shared__ float gs[DIM];
    __shared__ float red[6];
    int gid = blockIdx.x;
    int t = threadIdx.x;

    gs[t] = g[(size_t)gid * DIM + t];
    __syncthreads();

    float acc = b1[t];
#pragma unroll
    for (int k = 0; k < DIM; ++k) acc = fmaf(gs[k], w1[k * DIM + t], acc);
    float h = fmaxf(acc, 0.f);

    float c0 = h * w2[t * 3 + 0];
    float c1 = h * w2[t * 3 + 1];
    float c2 = h * w2[t * 3 + 2];
#pragma unroll
    for (int off = 32; off >= 1; off >>= 1) {
        c0 += __shfl_down(c0, off);
        c1 += __shfl_down(c1, off);
        c2 += __shfl_down(c2, off);
    }
    int wave = t >> 6;
    if ((t & 63) == 0) {
        red[wave * 3 + 0] = c0;
        red[wave * 3 + 1] = c1;
        red[wave * 3 + 2] = c2;
    }
    __syncthreads();
    if (t == 0) {
        out[(size_t)gid * 3 + 0] = red[0] + red[3] + b2[0];
        out[(size_t)gid * 3 + 1] = red[1] + red[4] + b2[1];
        out[(size_t)gid * 3 + 2] = red[2] + red[5] + b2[2];
    }
}

// ===========================================================================
extern "C" void kernel_launch(void* const* d_in, const int* in_sizes, int n_in,
                              void* d_out, int out_size, void* d_ws, size_t ws_size,
                              hipStream_t stream)
{
    const float* x       = (const float*)d_in[0];
    const int*   eidx    = (const int*)d_in[1];
    const int*   batch   = (const int*)d_in[2];
    const float* gin_w1  = (const float*)d_in[3];
    const float* gin_b1  = (const float*)d_in[4];
    const float* gin_w2  = (const float*)d_in[5];
    const float* gin_b2  = (const float*)d_in[6];
    const float* gcn_w   = (const float*)d_in[7];
    const float* gcn_b   = (const float*)d_in[8];
    const float* lin1_w  = (const float*)d_in[9];
    const float* lin1_b  = (const float*)d_in[10];
    const float* lin2_w  = (const float*)d_in[11];
    const float* lin2_b  = (const float*)d_in[12];

    const int* src = eidx;
    const int* dst = eidx + N_EDGES;

    // workspace carve (256B aligned)
    const size_t NB = (size_t)N_NODES * DIM * sizeof(float);   // 51.2 MB
    char* base = (char*)d_ws;
    size_t off = 0;
    auto carve = [&](size_t bytes) {
        char* p = base + off;
        off = (off + bytes + 255) & ~(size_t)255;
        return p;
    };
    float* bufA   = (float*)carve(NB);                         // gathered H
    float* bufB   = (float*)carve(NB);                         // u rows
    int*   cnt    = (int*)  carve(N_NODES * sizeof(int));      // cnt -> dinv
    int*   rp     = (int*)  carve((N_NODES + 1) * sizeof(int));
    int*   cursor = (int*)  carve(N_NODES * sizeof(int));
    int*   csr    = (int*)  carve((size_t)N_EDGES * sizeof(int));
    int*   bsum   = (int*)  carve(SCAN_NBLK * sizeof(int));
    float* g      = (float*)carve((size_t)N_GRAPHS * DIM * sizeof(float));
    float* dinv   = (float*)cnt;   // in-place conversion in scan3

    hipMemsetAsync(cnt, 0, N_NODES * sizeof(int), stream);
    hipMemsetAsync(g, 0, (size_t)N_GRAPHS * DIM * sizeof(float), stream);

    const int egrid4 = (N_EDGES / 4 + 255) / 256;
    const int ngrid  = (N_NODES + 7) / 8;
    const int mgrid  = (N_NODES + MB - 1) / MB;
    const int pgrid  = (N_NODES + P2_NODES - 1) / P2_NODES;

    // ---- CSR build ----
    cnt_kernel<<<egrid4, 256, 0, stream>>>(dst, cnt, N_EDGES);
    scan1<<<SCAN_NBLK, SCAN_T, 0, stream>>>(cnt, rp, bsum, N_NODES);
    scan2<<<1, 128, 0, stream>>>(bsum, SCAN_NBLK);
    scan3<<<(N_NODES + 256) / 256, 256, 0, stream>>>(rp, cursor, bsum, cnt,
                                                     N_NODES, N_EDGES);
    csr_fill<<<FILL_RANGES * 128, 256, 0, stream>>>(src, dst, cursor, csr, N_EDGES);

    // ---- GIN gather (high occupancy) ----
    csr_gather<<<ngrid, 256, 0, stream>>>(rp, csr, x, bufA, N_NODES);

    // ---- fused 3-layer MLP -> u ----
    mlp3<<<mgrid, 256, 0, stream>>>(bufA, gin_w1, gin_b1, gin_w2, gin_b2,
                                    gcn_w, dinv, bufB, N_NODES);

    // ---- fused GCN gather + finalize + pool -> g ----
    gcn_gather_pool<<<pgrid, 256, 0, stream>>>(rp, csr, bufB, dinv, gcn_b,
                                               batch, g, N_NODES);

    // ---- head ----
    head_kernel<<<N_GRAPHS, 128, 0, stream>>>(
        g, lin1_w, lin1_b, lin2_w, lin2_b, (float*)d_out);
}

// Round 7
// 664.294 us; speedup vs baseline: 1.0204x; 1.0204x over previous
//
#include <hip/hip_runtime.h>
#include <hip/hip_bf16.h>

// Problem constants (match reference)
#define N_NODES  100000
#define N_EDGES  1600000
#define N_GRAPHS 2048
#define DIM      128   // IN_DIM == HIDDEN == 128

// ===========================================================================
// CSR construction: count -> 3-phase exclusive scan -> XCD-partitioned fill
// ===========================================================================
__global__ __launch_bounds__(256)
void cnt_kernel(const int* __restrict__ dst, int* __restrict__ cnt, int E)
{
    int e0 = (blockIdx.x * blockDim.x + threadIdx.x) * 4;
    if (e0 + 3 < E) {
        int4 d = *(const int4*)&dst[e0];
        atomicAdd(&cnt[d.x], 1);
        atomicAdd(&cnt[d.y], 1);
        atomicAdd(&cnt[d.z], 1);
        atomicAdd(&cnt[d.w], 1);
    } else {
        for (int e = e0; e < E; ++e) atomicAdd(&cnt[dst[e]], 1);
    }
}

#define SCAN_T     256
#define SCAN_E     4
#define SCAN_CHUNK 1024   // SCAN_T * SCAN_E
#define SCAN_NBLK  ((N_NODES + SCAN_CHUNK - 1) / SCAN_CHUNK)   // 98

__global__ __launch_bounds__(SCAN_T)
void scan1(const int* __restrict__ cnt, int* __restrict__ rp,
           int* __restrict__ bsum, int N)
{
    __shared__ int sh[SCAN_T];
    int b = blockIdx.x, t = threadIdx.x;
    int base = b * SCAN_CHUNK + t * SCAN_E;
    int v[SCAN_E];
    int s = 0;
#pragma unroll
    for (int i = 0; i < SCAN_E; ++i) {
        int idx = base + i;
        v[i] = (idx < N) ? cnt[idx] : 0;
        s += v[i];
    }
    sh[t] = s;
    __syncthreads();
    for (int off = 1; off < SCAN_T; off <<= 1) {
        int add = (t >= off) ? sh[t - off] : 0;
        __syncthreads();
        sh[t] += add;
        __syncthreads();
    }
    int excl = sh[t] - s;
    if (t == SCAN_T - 1) bsum[b] = sh[t];
    int run = excl;
#pragma unroll
    for (int i = 0; i < SCAN_E; ++i) {
        int idx = base + i;
        if (idx < N) rp[idx] = run;
        run += v[i];
    }
}

__global__ __launch_bounds__(128)
void scan2(int* __restrict__ bsum, int nb)
{
    __shared__ int sh[128];
    int t = threadIdx.x;
    int v = (t < nb) ? bsum[t] : 0;
    sh[t] = v;
    __syncthreads();
    for (int off = 1; off < 128; off <<= 1) {
        int add = (t >= off) ? sh[t - off] : 0;
        __syncthreads();
        sh[t] += add;
        __syncthreads();
    }
    if (t < nb) bsum[t] = sh[t] - v;   // exclusive
}

// Phase 3: add block offsets; emit row_ptr + cursor; also cnt -> dinv (fused)
__global__ __launch_bounds__(256)
void scan3(int* __restrict__ rp, int* __restrict__ cursor,
           const int* __restrict__ bsum, int* __restrict__ cnt, int N, int E)
{
    int i = blockIdx.x * blockDim.x + threadIdx.x;
    if (i < N) {
        int v = rp[i] + bsum[i / SCAN_CHUNK];
        rp[i] = v;
        cursor[i] = v;
        float d = (float)cnt[i] + 1.0f;
        ((float*)cnt)[i] = rsqrtf(d);   // in-place: cnt buffer becomes dinv
    }
    if (i == N) rp[N] = E;
}

// XCD-partitioned fill (round-4 win: keeps csr-line fills within one XCD L2)
#define FILL_RANGES 8
#define FILL_RSIZE  (N_NODES / FILL_RANGES)   // 12500 exact
__global__ __launch_bounds__(256)
void csr_fill(const int* __restrict__ src, const int* __restrict__ dst,
              int* __restrict__ cursor, int* __restrict__ csr, int E)
{
    const int r = blockIdx.x & (FILL_RANGES - 1);
    const int s = blockIdx.x >> 3;
    const int nslice = gridDim.x >> 3;
    const unsigned lo = (unsigned)(r * FILL_RSIZE);
    const int stride = nslice * 256 * 4;

    for (int e0 = (s * 256 + threadIdx.x) * 4; e0 < E; e0 += stride) {
        int4 d  = *(const int4*)&dst[e0];
        int4 sv = *(const int4*)&src[e0];
        if ((unsigned)(d.x - lo) < (unsigned)FILL_RSIZE) {
            int p = atomicAdd(&cursor[d.x], 1); csr[p] = sv.x;
        }
        if ((unsigned)(d.y - lo) < (unsigned)FILL_RSIZE) {
            int p = atomicAdd(&cursor[d.y], 1); csr[p] = sv.y;
        }
        if ((unsigned)(d.z - lo) < (unsigned)FILL_RSIZE) {
            int p = atomicAdd(&cursor[d.z], 1); csr[p] = sv.z;
        }
        if ((unsigned)(d.w - lo) < (unsigned)FILL_RSIZE) {
            int p = atomicAdd(&cursor[d.w], 1); csr[p] = sv.w;
        }
    }
}

// ===========================================================================
// CSR gather: Out[i] = V[i] + sum_{e in [rp[i],rp[i+1])} V[csr[e]]
// One node per 32-lane group, float4 per lane, x4 unroll. No LDS -> high
// occupancy (the memory-parallelism this latency/BW-bound kernel needs).
// ===========================================================================
__global__ __launch_bounds__(256)
void csr_gather(const int* __restrict__ rp, const int* __restrict__ csr,
                const float* __restrict__ V, float* __restrict__ Out, int N)
{
    int node = blockIdx.x * 8 + (threadIdx.x >> 5);
    int lane = threadIdx.x & 31;
    if (node >= N) return;
    int beg = rp[node];
    int end = rp[node + 1];
    const float4* V4 = (const float4*)V;
    float4 acc = V4[(size_t)node * 32 + lane];   // self term
    int e = beg;
    for (; e + 4 <= end; e += 4) {
        int s0 = csr[e + 0];
        int s1 = csr[e + 1];
        int s2 = csr[e + 2];
        int s3 = csr[e + 3];
        float4 v0 = V4[(size_t)s0 * 32 + lane];
        float4 v1 = V4[(size_t)s1 * 32 + lane];
        float4 v2 = V4[(size_t)s2 * 32 + lane];
        float4 v3 = V4[(size_t)s3 * 32 + lane];
        acc.x += v0.x + v1.x + v2.x + v3.x;
        acc.y += v0.y + v1.y + v2.y + v3.y;
        acc.z += v0.z + v1.z + v2.z + v3.z;
        acc.w += v0.w + v1.w + v2.w + v3.w;
    }
    for (; e < end; ++e) {
        int s = csr[e];
        float4 v = V4[(size_t)s * 32 + lane];
        acc.x += v.x; acc.y += v.y; acc.z += v.z; acc.w += v.w;
    }
    ((float4*)Out)[(size_t)node * 32 + lane] = acc;
}

// ===========================================================================
// Fused 3-layer MLP v2 — issue-efficiency rebuild:
//   128 threads, 64 rows/block, 8x8 thread tile (2x FMA per operand fetch),
//   a-operand read as b128 over k-chunks of 4, W read straight from global
//   (L2-resident 64 KB, 512B-coalesced, shared via L1) -> no Ws staging, no
//   per-chunk barriers (2 per layer), LDS = H only (33.8 KB -> 4 blocks/CU).
//   L0: H = relu(H @ w1 + b1); L1: H = relu(H @ w2 + b2)
//   L2: u = dinv[row] * (H @ w3) -> global
// ===========================================================================
#define MB    64
#define HP    132   // row stride: 132*4 B, 16B-aligned for b128

__global__ __launch_bounds__(128)
void mlp3(const float* __restrict__ Hin,
          const float* __restrict__ w1, const float* __restrict__ b1,
          const float* __restrict__ w2, const float* __restrict__ b2,
          const float* __restrict__ w3, const float* __restrict__ dinv,
          float* __restrict__ u_out, int N)
{
    __shared__ float H[MB][HP];

    const int tid  = threadIdx.x;
    const int tx   = tid & 15;    // 16 col groups * 8 = 128
    const int ty   = tid >> 4;    // 8 row groups * 8 = 64
    const int row0 = blockIdx.x * MB;

    // ---- load H tile (coalesced): 2048 float4, 16/thread ----
#pragma unroll
    for (int l = 0; l < 16; ++l) {
        int f  = tid + l * 128;
        int r  = f >> 5;              // 0..63
        int c4 = (f & 31) << 2;       // 0..124
        int gr = row0 + r;
        float4 v = make_float4(0.f, 0.f, 0.f, 0.f);
        if (gr < N) v = *(const float4*)&Hin[(size_t)gr * DIM + c4];
        *(float4*)&H[r][c4] = v;
    }
    __syncthreads();

    for (int layer = 0; layer < 3; ++layer) {
        const float* __restrict__ W =
            (layer == 0) ? w1 : (layer == 1) ? w2 : w3;

        float acc[8][8];
        if (layer < 2) {
            const float* bias = (layer == 0) ? b1 : b2;
            float bv[8];
#pragma unroll
            for (int j = 0; j < 8; ++j) bv[j] = bias[tx * 8 + j];
#pragma unroll
            for (int i = 0; i < 8; ++i)
#pragma unroll
                for (int j = 0; j < 8; ++j) acc[i][j] = bv[j];
        } else {
#pragma unroll
            for (int i = 0; i < 8; ++i)
#pragma unroll
                for (int j = 0; j < 8; ++j) acc[i][j] = 0.f;
        }

        for (int k4 = 0; k4 < 32; ++k4) {
            // a: 8 rows x 4 k as b128 LDS reads
            float4 av[8];
#pragma unroll
            for (int i = 0; i < 8; ++i)
                av[i] = *(const float4*)&H[ty * 8 + i][k4 * 4];
            // b: 4 W rows x 8 cols from global (coalesced 512B, L1/L2-hot)
            float4 bv0[4], bv1[4];
            const float* wbase = W + (size_t)(k4 * 4) * DIM + tx * 8;
#pragma unroll
            for (int q = 0; q < 4; ++q) {
                bv0[q] = *(const float4*)(wbase + q * DIM);
                bv1[q] = *(const float4*)(wbase + q * DIM + 4);
            }
#pragma unroll
            for (int q = 0; q < 4; ++q) {
                float bj[8];
                bj[0] = bv0[q].x; bj[1] = bv0[q].y;
                bj[2] = bv0[q].z; bj[3] = bv0[q].w;
                bj[4] = bv1[q].x; bj[5] = bv1[q].y;
                bj[6] = bv1[q].z; bj[7] = bv1[q].w;
#pragma unroll
                for (int i = 0; i < 8; ++i) {
                    float a = ((const float*)&av[i])[q];
#pragma unroll
                    for (int j = 0; j < 8; ++j)
                        acc[i][j] = fmaf(a, bj[j], acc[i][j]);
                }
            }
        }
        __syncthreads();   // all H reads done before overwrite / next layer

        if (layer < 2) {
#pragma unroll
            for (int i = 0; i < 8; ++i) {
                float4 v0, v1;
                v0.x = fmaxf(acc[i][0], 0.f); v0.y = fmaxf(acc[i][1], 0.f);
                v0.z = fmaxf(acc[i][2], 0.f); v0.w = fmaxf(acc[i][3], 0.f);
                v1.x = fmaxf(acc[i][4], 0.f); v1.y = fmaxf(acc[i][5], 0.f);
                v1.z = fmaxf(acc[i][6], 0.f); v1.w = fmaxf(acc[i][7], 0.f);
                *(float4*)&H[ty * 8 + i][tx * 8 + 0] = v0;
                *(float4*)&H[ty * 8 + i][tx * 8 + 4] = v1;
            }
            __syncthreads();
        } else {
            // u = dinv * (H @ w3), coalesced float4 x2 store
#pragma unroll
            for (int i = 0; i < 8; ++i) {
                int r = row0 + ty * 8 + i;
                if (r < N) {
                    float di = dinv[r];
                    float4 v0, v1;
                    v0.x = di * acc[i][0]; v0.y = di * acc[i][1];
                    v0.z = di * acc[i][2]; v0.w = di * acc[i][3];
                    v1.x = di * acc[i][4]; v1.y = di * acc[i][5];
                    v1.z = di * acc[i][6]; v1.w = di * acc[i][7];
                    *(float4*)&u_out[(size_t)r * DIM + tx * 8 + 0] = v0;
                    *(float4*)&u_out[(size_t)r * DIM + tx * 8 + 4] = v1;
                }
            }
        }
    }
}

// ===========================================================================
// Fused GCN gather + finalize + global_add_pool:
//   h_i = relu(dinv_i * (u_i + sum u[csr]) + b);  g[batch[i]] += h_i
// ===========================================================================
#define P2_NODES 64
__global__ __launch_bounds__(256)
void gcn_gather_pool(const int* __restrict__ rp, const int* __restrict__ csr,
                     const float* __restrict__ u, const float* __restrict__ dinv,
                     const float* __restrict__ bias, const int* __restrict__ batch,
                     float* __restrict__ g, int N)
{
    const int grp  = threadIdx.x >> 5;
    const int lane = threadIdx.x & 31;
    const int n0   = blockIdx.x * P2_NODES + grp * 8;
    const float4* V4 = (const float4*)u;

    float4 bj;
    bj.x = bias[lane * 4 + 0];
    bj.y = bias[lane * 4 + 1];
    bj.z = bias[lane * 4 + 2];
    bj.w = bias[lane * 4 + 3];

    float4 lsum = make_float4(0.f, 0.f, 0.f, 0.f);
    int prev = -1;

    for (int k = 0; k < 8; ++k) {
        int node = n0 + k;
        if (node >= N) break;
        float4 acc = V4[(size_t)node * 32 + lane];   // self term u_i
        int e = rp[node], end = rp[node + 1];
        for (; e + 4 <= end; e += 4) {
            int s0 = csr[e + 0], s1 = csr[e + 1];
            int s2 = csr[e + 2], s3 = csr[e + 3];
            float4 v0 = V4[(size_t)s0 * 32 + lane];
            float4 v1 = V4[(size_t)s1 * 32 + lane];
            float4 v2 = V4[(size_t)s2 * 32 + lane];
            float4 v3 = V4[(size_t)s3 * 32 + lane];
            acc.x += v0.x + v1.x + v2.x + v3.x;
            acc.y += v0.y + v1.y + v2.y + v3.y;
            acc.z += v0.z + v1.z + v2.z + v3.z;
            acc.w += v0.w + v1.w + v2.w + v3.w;
        }
        for (; e < end; ++e) {
            int s = csr[e];
            float4 v = V4[(size_t)s * 32 + lane];
            acc.x += v.x; acc.y += v.y; acc.z += v.z; acc.w += v.w;
        }
        float di = dinv[node];
        float4 h;
        h.x = fmaxf(fmaf(di, acc.x, bj.x), 0.f);
        h.y = fmaxf(fmaf(di, acc.y, bj.y), 0.f);
        h.z = fmaxf(fmaf(di, acc.z, bj.z), 0.f);
        h.w = fmaxf(fmaf(di, acc.w, bj.w), 0.f);

        int b = batch[node];
        if (b != prev) {
            if (prev >= 0) {
                float* gp = &g[(size_t)prev * DIM + lane * 4];
                atomicAdd(gp + 0, lsum.x);
                atomicAdd(gp + 1, lsum.y);
                atomicAdd(gp + 2, lsum.z);
                atomicAdd(gp + 3, lsum.w);
            }
            lsum = make_float4(0.f, 0.f, 0.f, 0.f);
            prev = b;
        }
        lsum.x += h.x; lsum.y += h.y; lsum.z += h.z; lsum.w += h.w;
    }
    if (prev >= 0) {
        float* gp = &g[(size_t)prev * DIM + lane * 4];
        atomicAdd(gp + 0, lsum.x);
        atomicAdd(gp + 1, lsum.y);
        atomicAdd(gp + 2, lsum.z);
        atomicAdd(gp + 3, lsum.w);
    }
}

// ===========================================================================
// Head: out[gid] = relu(g[gid] @ lin1_w + b1) @ lin2_w + b2
// ===========================================================================
__global__ __launch_bounds__(128)
void head_kernel(const float* __restrict__ g, const float* __restrict__ w1,
                 const float* __restrict__ b1, const float* __restrict__ w2,
                 const float* __restrict__ b2, float* __restrict__ out)
{
    __shared__ float gs[DIM];
    __shared__ float red[6];
    int gid = blockIdx.x;
    int t = threadIdx.x;

    gs[t] = g[(size_t)gid * DIM + t];
    __syncthreads();

    float acc = b1[t];
#pragma unroll
    for (int k = 0; k < DIM; ++k) acc = fmaf(gs[k], w1[k * DIM + t], acc);
    float h = fmaxf(acc, 0.f);

    float c0 = h * w2[t * 3 + 0];
    float c1 = h * w2[t * 3 + 1];
    float c2 = h * w2[t * 3 + 2];
#pragma unroll
    for (int off = 32; off >= 1; off >>= 1) {
        c0 += __shfl_down(c0, off);
        c1 += __shfl_down(c1, off);
        c2 += __shfl_down(c2, off);
    }
    int wave = t >> 6;
    if ((t & 63) == 0) {
        red[wave * 3 + 0] = c0;
        red[wave * 3 + 1] = c1;
        red[wave * 3 + 2] = c2;
    }
    __syncthreads();
    if (t == 0) {
        out[(size_t)gid * 3 + 0] = red[0] + red[3] + b2[0];
        out[(size_t)gid * 3 + 1] = red[1] + red[4] + b2[1];
        out[(size_t)gid * 3 + 2] = red[2] + red[5] + b2[2];
    }
}

// ===========================================================================
extern "C" void kernel_launch(void* const* d_in, const int* in_sizes, int n_in,
                              void* d_out, int out_size, void* d_ws, size_t ws_size,
                              hipStream_t stream)
{
    const float* x       = (const float*)d_in[0];
    const int*   eidx    = (const int*)d_in[1];
    const int*   batch   = (const int*)d_in[2];
    const float* gin_w1  = (const float*)d_in[3];
    const float* gin_b1  = (const float*)d_in[4];
    const float* gin_w2  = (const float*)d_in[5];
    const float* gin_b2  = (const float*)d_in[6];
    const float* gcn_w   = (const float*)d_in[7];
    const float* gcn_b   = (const float*)d_in[8];
    const float* lin1_w  = (const float*)d_in[9];
    const float* lin1_b  = (const float*)d_in[10];
    const float* lin2_w  = (const float*)d_in[11];
    const float* lin2_b  = (const float*)d_in[12];

    const int* src = eidx;
    const int* dst = eidx + N_EDGES;

    // workspace carve (256B aligned)
    const size_t NB = (size_t)N_NODES * DIM * sizeof(float);   // 51.2 MB
    char* base = (char*)d_ws;
    size_t off = 0;
    auto carve = [&](size_t bytes) {
        char* p = base + off;
        off = (off + bytes + 255) & ~(size_t)255;
        return p;
    };
    float* bufA   = (float*)carve(NB);                         // gathered H
    float* bufB   = (float*)carve(NB);                         // u rows
    int*   cnt    = (int*)  carve(N_NODES * sizeof(int));      // cnt -> dinv
    int*   rp     = (int*)  carve((N_NODES + 1) * sizeof(int));
    int*   cursor = (int*)  carve(N_NODES * sizeof(int));
    int*   csr    = (int*)  carve((size_t)N_EDGES * sizeof(int));
    int*   bsum   = (int*)  carve(SCAN_NBLK * sizeof(int));
    float* g      = (float*)carve((size_t)N_GRAPHS * DIM * sizeof(float));
    float* dinv   = (float*)cnt;   // in-place conversion in scan3

    hipMemsetAsync(cnt, 0, N_NODES * sizeof(int), stream);
    hipMemsetAsync(g, 0, (size_t)N_GRAPHS * DIM * sizeof(float), stream);

    const int egrid4 = (N_EDGES / 4 + 255) / 256;
    const int ngrid  = (N_NODES + 7) / 8;
    const int mgrid  = (N_NODES + MB - 1) / MB;
    const int pgrid  = (N_NODES + P2_NODES - 1) / P2_NODES;

    // ---- CSR build ----
    cnt_kernel<<<egrid4, 256, 0, stream>>>(dst, cnt, N_EDGES);
    scan1<<<SCAN_NBLK, SCAN_T, 0, stream>>>(cnt, rp, bsum, N_NODES);
    scan2<<<1, 128, 0, stream>>>(bsum, SCAN_NBLK);
    scan3<<<(N_NODES + 256) / 256, 256, 0, stream>>>(rp, cursor, bsum, cnt,
                                                     N_NODES, N_EDGES);
    csr_fill<<<FILL_RANGES * 128, 256, 0, stream>>>(src, dst, cursor, csr, N_EDGES);

    // ---- GIN gather (high occupancy) ----
    csr_gather<<<ngrid, 256, 0, stream>>>(rp, csr, x, bufA, N_NODES);

    // ---- fused 3-layer MLP -> u ----
    mlp3<<<mgrid, 128, 0, stream>>>(bufA, gin_w1, gin_b1, gin_w2, gin_b2,
                                    gcn_w, dinv, bufB, N_NODES);

    // ---- fused GCN gather + finalize + pool -> g ----
    gcn_gather_pool<<<pgrid, 256, 0, stream>>>(rp, csr, bufB, dinv, gcn_b,
                                               batch, g, N_NODES);

    // ---- head ----
    head_kernel<<<N_GRAPHS, 128, 0, stream>>>(
        g, lin1_w, lin1_b, lin2_w, lin2_b, (float*)d_out);
}

// Round 8
// 565.758 us; speedup vs baseline: 1.1981x; 1.1742x over previous
//
#include <hip/hip_runtime.h>
#include <hip/hip_bf16.h>

// Problem constants (match reference)
#define N_NODES  100000
#define N_EDGES  1600000
#define N_GRAPHS 2048
#define DIM      128   // IN_DIM == HIDDEN == 128

// ---- bf16 helpers (RNE encode, bit-shift decode) --------------------------
__device__ __forceinline__ unsigned short f2b(float f) {
    unsigned u = __float_as_uint(f);
    u += 0x7FFFu + ((u >> 16) & 1u);
    return (unsigned short)(u >> 16);
}
__device__ __forceinline__ float b2f(unsigned short h) {
    return __uint_as_float(((unsigned)h) << 16);
}
__device__ __forceinline__ float4 dec4(ushort4 h) {
    return make_float4(b2f(h.x), b2f(h.y), b2f(h.z), b2f(h.w));
}

// ===========================================================================
// Cast fp32 -> bf16 (8 elems/thread): 12.8M elems, ~13 us
// ===========================================================================
__global__ __launch_bounds__(256)
void cast_bf16(const float* __restrict__ in, unsigned short* __restrict__ out,
               int n8)
{
    int i = blockIdx.x * 256 + threadIdx.x;
    if (i >= n8) return;
    const float4* in4 = (const float4*)in;
    float4 a = in4[i * 2 + 0];
    float4 b = in4[i * 2 + 1];
    uint4 q;
    q.x = (unsigned)f2b(a.x) | ((unsigned)f2b(a.y) << 16);
    q.y = (unsigned)f2b(a.z) | ((unsigned)f2b(a.w) << 16);
    q.z = (unsigned)f2b(b.x) | ((unsigned)f2b(b.y) << 16);
    q.w = (unsigned)f2b(b.z) | ((unsigned)f2b(b.w) << 16);
    ((uint4*)out)[i] = q;
}

// ===========================================================================
// CSR construction. cnt is now XCD-partitioned like csr_fill (round-4 win):
// all atomics for a counter range stay in one XCD's L2.
// ===========================================================================
#define FILL_RANGES 8
#define FILL_RSIZE  (N_NODES / FILL_RANGES)   // 12500 exact

__global__ __launch_bounds__(256)
void cnt_kernel(const int* __restrict__ dst, int* __restrict__ cnt, int E)
{
    const int r = blockIdx.x & (FILL_RANGES - 1);
    const int s = blockIdx.x >> 3;
    const int nslice = gridDim.x >> 3;
    const unsigned lo = (unsigned)(r * FILL_RSIZE);
    const int stride = nslice * 256 * 4;

    for (int e0 = (s * 256 + threadIdx.x) * 4; e0 < E; e0 += stride) {
        int4 d = *(const int4*)&dst[e0];
        if ((unsigned)(d.x - lo) < (unsigned)FILL_RSIZE) atomicAdd(&cnt[d.x], 1);
        if ((unsigned)(d.y - lo) < (unsigned)FILL_RSIZE) atomicAdd(&cnt[d.y], 1);
        if ((unsigned)(d.z - lo) < (unsigned)FILL_RSIZE) atomicAdd(&cnt[d.z], 1);
        if ((unsigned)(d.w - lo) < (unsigned)FILL_RSIZE) atomicAdd(&cnt[d.w], 1);
    }
}

#define SCAN_T     256
#define SCAN_E     4
#define SCAN_CHUNK 1024   // SCAN_T * SCAN_E
#define SCAN_NBLK  ((N_NODES + SCAN_CHUNK - 1) / SCAN_CHUNK)   // 98

__global__ __launch_bounds__(SCAN_T)
void scan1(const int* __restrict__ cnt, int* __restrict__ rp,
           int* __restrict__ bsum, int N)
{
    __shared__ int sh[SCAN_T];
    int b = blockIdx.x, t = threadIdx.x;
    int base = b * SCAN_CHUNK + t * SCAN_E;
    int v[SCAN_E];
    int s = 0;
#pragma unroll
    for (int i = 0; i < SCAN_E; ++i) {
        int idx = base + i;
        v[i] = (idx < N) ? cnt[idx] : 0;
        s += v[i];
    }
    sh[t] = s;
    __syncthreads();
    for (int off = 1; off < SCAN_T; off <<= 1) {
        int add = (t >= off) ? sh[t - off] : 0;
        __syncthreads();
        sh[t] += add;
        __syncthreads();
    }
    int excl = sh[t] - s;
    if (t == SCAN_T - 1) bsum[b] = sh[t];
    int run = excl;
#pragma unroll
    for (int i = 0; i < SCAN_E; ++i) {
        int idx = base + i;
        if (idx < N) rp[idx] = run;
        run += v[i];
    }
}

__global__ __launch_bounds__(128)
void scan2(int* __restrict__ bsum, int nb)
{
    __shared__ int sh[128];
    int t = threadIdx.x;
    int v = (t < nb) ? bsum[t] : 0;
    sh[t] = v;
    __syncthreads();
    for (int off = 1; off < 128; off <<= 1) {
        int add = (t >= off) ? sh[t - off] : 0;
        __syncthreads();
        sh[t] += add;
        __syncthreads();
    }
    if (t < nb) bsum[t] = sh[t] - v;   // exclusive
}

// Phase 3: add block offsets; emit row_ptr + cursor; also cnt -> dinv (fused)
__global__ __launch_bounds__(256)
void scan3(int* __restrict__ rp, int* __restrict__ cursor,
           const int* __restrict__ bsum, int* __restrict__ cnt, int N, int E)
{
    int i = blockIdx.x * blockDim.x + threadIdx.x;
    if (i < N) {
        int v = rp[i] + bsum[i / SCAN_CHUNK];
        rp[i] = v;
        cursor[i] = v;
        float d = (float)cnt[i] + 1.0f;
        ((float*)cnt)[i] = rsqrtf(d);   // in-place: cnt buffer becomes dinv
    }
    if (i == N) rp[N] = E;
}

// XCD-partitioned fill
__global__ __launch_bounds__(256)
void csr_fill(const int* __restrict__ src, const int* __restrict__ dst,
              int* __restrict__ cursor, int* __restrict__ csr, int E)
{
    const int r = blockIdx.x & (FILL_RANGES - 1);
    const int s = blockIdx.x >> 3;
    const int nslice = gridDim.x >> 3;
    const unsigned lo = (unsigned)(r * FILL_RSIZE);
    const int stride = nslice * 256 * 4;

    for (int e0 = (s * 256 + threadIdx.x) * 4; e0 < E; e0 += stride) {
        int4 d  = *(const int4*)&dst[e0];
        int4 sv = *(const int4*)&src[e0];
        if ((unsigned)(d.x - lo) < (unsigned)FILL_RSIZE) {
            int p = atomicAdd(&cursor[d.x], 1); csr[p] = sv.x;
        }
        if ((unsigned)(d.y - lo) < (unsigned)FILL_RSIZE) {
            int p = atomicAdd(&cursor[d.y], 1); csr[p] = sv.y;
        }
        if ((unsigned)(d.z - lo) < (unsigned)FILL_RSIZE) {
            int p = atomicAdd(&cursor[d.z], 1); csr[p] = sv.z;
        }
        if ((unsigned)(d.w - lo) < (unsigned)FILL_RSIZE) {
            int p = atomicAdd(&cursor[d.w], 1); csr[p] = sv.w;
        }
    }
}

// ===========================================================================
// bf16 CSR gather: Out[i] = Vb[i] + sum Vb[csr[e]]  (fp32 accumulate)
// bf16 rows are 256 B -> halves the random-read L2-miss traffic vs fp32.
// One node per 32-lane group, ushort4 (8 B) per lane, x4 unroll.
// ===========================================================================
__global__ __launch_bounds__(256)
void csr_gather_b(const int* __restrict__ rp, const int* __restrict__ csr,
                  const unsigned short* __restrict__ Vb,
                  float* __restrict__ Out, int N)
{
    int node = blockIdx.x * 8 + (threadIdx.x >> 5);
    int lane = threadIdx.x & 31;
    if (node >= N) return;
    int beg = rp[node];
    int end = rp[node + 1];
    const ushort4* V4 = (const ushort4*)Vb;   // 32 ushort4 per row
    float4 acc = dec4(V4[(size_t)node * 32 + lane]);   // self term
    int e = beg;
    for (; e + 4 <= end; e += 4) {
        int s0 = csr[e + 0];
        int s1 = csr[e + 1];
        int s2 = csr[e + 2];
        int s3 = csr[e + 3];
        float4 v0 = dec4(V4[(size_t)s0 * 32 + lane]);
        float4 v1 = dec4(V4[(size_t)s1 * 32 + lane]);
        float4 v2 = dec4(V4[(size_t)s2 * 32 + lane]);
        float4 v3 = dec4(V4[(size_t)s3 * 32 + lane]);
        acc.x += v0.x + v1.x + v2.x + v3.x;
        acc.y += v0.y + v1.y + v2.y + v3.y;
        acc.z += v0.z + v1.z + v2.z + v3.z;
        acc.w += v0.w + v1.w + v2.w + v3.w;
    }
    for (; e < end; ++e) {
        int s = csr[e];
        float4 v = dec4(V4[(size_t)s * 32 + lane]);
        acc.x += v.x; acc.y += v.y; acc.z += v.z; acc.w += v.w;
    }
    ((float4*)Out)[(size_t)node * 32 + lane] = acc;
}

// ===========================================================================
// Fused 3-layer MLP v3: 8x8 tile + register-prefetched W (software pipeline:
// W loads for k4+1 issued before the 512-cycle FMA block of k4, consumed at
// top of next iteration -> L2 latency hidden inside one wave).
//   L0: H = relu(H @ w1 + b1); L1: H = relu(H @ w2 + b2)
//   L2: u = dinv[row] * (H @ w3) -> global as bf16 (feeds bf16 gather2)
// ===========================================================================
#define MB    64
#define HP    132   // row stride: 132*4 B, 16B-aligned for b128

__global__ __launch_bounds__(128, 2)
void mlp3(const float* __restrict__ Hin,
          const float* __restrict__ w1, const float* __restrict__ b1,
          const float* __restrict__ w2, const float* __restrict__ b2,
          const float* __restrict__ w3, const float* __restrict__ dinv,
          unsigned short* __restrict__ ub_out, int N)
{
    __shared__ float H[MB][HP];

    const int tid  = threadIdx.x;
    const int tx   = tid & 15;    // 16 col groups * 8 = 128
    const int ty   = tid >> 4;    // 8 row groups * 8 = 64
    const int row0 = blockIdx.x * MB;

    // ---- load H tile (coalesced): 2048 float4, 16/thread ----
#pragma unroll
    for (int l = 0; l < 16; ++l) {
        int f  = tid + l * 128;
        int r  = f >> 5;              // 0..63
        int c4 = (f & 31) << 2;       // 0..124
        int gr = row0 + r;
        float4 v = make_float4(0.f, 0.f, 0.f, 0.f);
        if (gr < N) v = *(const float4*)&Hin[(size_t)gr * DIM + c4];
        *(float4*)&H[r][c4] = v;
    }
    __syncthreads();

    for (int layer = 0; layer < 3; ++layer) {
        const float* __restrict__ W =
            (layer == 0) ? w1 : (layer == 1) ? w2 : w3;

        float acc[8][8];
        if (layer < 2) {
            const float* bias = (layer == 0) ? b1 : b2;
            float bv[8];
#pragma unroll
            for (int j = 0; j < 8; ++j) bv[j] = bias[tx * 8 + j];
#pragma unroll
            for (int i = 0; i < 8; ++i)
#pragma unroll
                for (int j = 0; j < 8; ++j) acc[i][j] = bv[j];
        } else {
#pragma unroll
            for (int i = 0; i < 8; ++i)
#pragma unroll
                for (int j = 0; j < 8; ++j) acc[i][j] = 0.f;
        }

        const float* wcol = W + tx * 8;
        // prologue prefetch k4=0
        float4 nb[8];
#pragma unroll
        for (int q = 0; q < 4; ++q) {
            nb[q]     = *(const float4*)(wcol + q * DIM);
            nb[q + 4] = *(const float4*)(wcol + q * DIM + 4);
        }

        for (int k4 = 0; k4 < 32; ++k4) {
            float4 cb[8];
#pragma unroll
            for (int q = 0; q < 8; ++q) cb[q] = nb[q];
            if (k4 < 31) {
                const float* wn = wcol + (size_t)(k4 + 1) * 4 * DIM;
#pragma unroll
                for (int q = 0; q < 4; ++q) {
                    nb[q]     = *(const float4*)(wn + q * DIM);
                    nb[q + 4] = *(const float4*)(wn + q * DIM + 4);
                }
            }
            float4 av[8];
#pragma unroll
            for (int i = 0; i < 8; ++i)
                av[i] = *(const float4*)&H[ty * 8 + i][k4 * 4];
#pragma unroll
            for (int q = 0; q < 4; ++q) {
                float bj[8];
                bj[0] = cb[q].x;     bj[1] = cb[q].y;
                bj[2] = cb[q].z;     bj[3] = cb[q].w;
                bj[4] = cb[q + 4].x; bj[5] = cb[q + 4].y;
                bj[6] = cb[q + 4].z; bj[7] = cb[q + 4].w;
#pragma unroll
                for (int i = 0; i < 8; ++i) {
                    float a = ((const float*)&av[i])[q];
#pragma unroll
                    for (int j = 0; j < 8; ++j)
                        acc[i][j] = fmaf(a, bj[j], acc[i][j]);
                }
            }
        }
        __syncthreads();   // all H reads done before overwrite / next layer

        if (layer < 2) {
#pragma unroll
            for (int i = 0; i < 8; ++i) {
                float4 v0, v1;
                v0.x = fmaxf(acc[i][0], 0.f); v0.y = fmaxf(acc[i][1], 0.f);
                v0.z = fmaxf(acc[i][2], 0.f); v0.w = fmaxf(acc[i][3], 0.f);
                v1.x = fmaxf(acc[i][4], 0.f); v1.y = fmaxf(acc[i][5], 0.f);
                v1.z = fmaxf(acc[i][6], 0.f); v1.w = fmaxf(acc[i][7], 0.f);
                *(float4*)&H[ty * 8 + i][tx * 8 + 0] = v0;
                *(float4*)&H[ty * 8 + i][tx * 8 + 4] = v1;
            }
            __syncthreads();
        } else {
            // u = dinv * (H @ w3) -> bf16 store (16 B per thread-row)
#pragma unroll
            for (int i = 0; i < 8; ++i) {
                int r = row0 + ty * 8 + i;
                if (r < N) {
                    float di = dinv[r];
                    uint4 q;
                    q.x = (unsigned)f2b(di * acc[i][0]) | ((unsigned)f2b(di * acc[i][1]) << 16);
                    q.y = (unsigned)f2b(di * acc[i][2]) | ((unsigned)f2b(di * acc[i][3]) << 16);
                    q.z = (unsigned)f2b(di * acc[i][4]) | ((unsigned)f2b(di * acc[i][5]) << 16);
                    q.w = (unsigned)f2b(di * acc[i][6]) | ((unsigned)f2b(di * acc[i][7]) << 16);
                    *(uint4*)&ub_out[(size_t)r * DIM + tx * 8] = q;
                }
            }
        }
    }
}

// ===========================================================================
// Fused GCN gather (bf16 u) + finalize + global_add_pool:
//   h_i = relu(dinv_i * (u_i + sum u[csr]) + b);  g[batch[i]] += h_i
// ===========================================================================
#define P2_NODES 64
__global__ __launch_bounds__(256)
void gcn_gather_pool(const int* __restrict__ rp, const int* __restrict__ csr,
                     const unsigned short* __restrict__ ub,
                     const float* __restrict__ dinv,
                     const float* __restrict__ bias, const int* __restrict__ batch,
                     float* __restrict__ g, int N)
{
    const int grp  = threadIdx.x >> 5;
    const int lane = threadIdx.x & 31;
    const int n0   = blockIdx.x * P2_NODES + grp * 8;
    const ushort4* V4 = (const ushort4*)ub;

    float4 bj;
    bj.x = bias[lane * 4 + 0];
    bj.y = bias[lane * 4 + 1];
    bj.z = bias[lane * 4 + 2];
    bj.w = bias[lane * 4 + 3];

    float4 lsum = make_float4(0.f, 0.f, 0.f, 0.f);
    int prev = -1;

    for (int k = 0; k < 8; ++k) {
        int node = n0 + k;
        if (node >= N) break;
        float4 acc = dec4(V4[(size_t)node * 32 + lane]);   // self term u_i
        int e = rp[node], end = rp[node + 1];
        for (; e + 4 <= end; e += 4) {
            int s0 = csr[e + 0], s1 = csr[e + 1];
            int s2 = csr[e + 2], s3 = csr[e + 3];
            float4 v0 = dec4(V4[(size_t)s0 * 32 + lane]);
            float4 v1 = dec4(V4[(size_t)s1 * 32 + lane]);
            float4 v2 = dec4(V4[(size_t)s2 * 32 + lane]);
            float4 v3 = dec4(V4[(size_t)s3 * 32 + lane]);
            acc.x += v0.x + v1.x + v2.x + v3.x;
            acc.y += v0.y + v1.y + v2.y + v3.y;
            acc.z += v0.z + v1.z + v2.z + v3.z;
            acc.w += v0.w + v1.w + v2.w + v3.w;
        }
        for (; e < end; ++e) {
            int s = csr[e];
            float4 v = dec4(V4[(size_t)s * 32 + lane]);
            acc.x += v.x; acc.y += v.y; acc.z += v.z; acc.w += v.w;
        }
        float di = dinv[node];
        float4 h;
        h.x = fmaxf(fmaf(di, acc.x, bj.x), 0.f);
        h.y = fmaxf(fmaf(di, acc.y, bj.y), 0.f);
        h.z = fmaxf(fmaf(di, acc.z, bj.z), 0.f);
        h.w = fmaxf(fmaf(di, acc.w, bj.w), 0.f);

        int b = batch[node];
        if (b != prev) {
            if (prev >= 0) {
                float* gp = &g[(size_t)prev * DIM + lane * 4];
                atomicAdd(gp + 0, lsum.x);
                atomicAdd(gp + 1, lsum.y);
                atomicAdd(gp + 2, lsum.z);
                atomicAdd(gp + 3, lsum.w);
            }
            lsum = make_float4(0.f, 0.f, 0.f, 0.f);
            prev = b;
        }
        lsum.x += h.x; lsum.y += h.y; lsum.z += h.z; lsum.w += h.w;
    }
    if (prev >= 0) {
        float* gp = &g[(size_t)prev * DIM + lane * 4];
        atomicAdd(gp + 0, lsum.x);
        atomicAdd(gp + 1, lsum.y);
        atomicAdd(gp + 2, lsum.z);
        atomicAdd(gp + 3, lsum.w);
    }
}

// ===========================================================================
// Head: out[gid] = relu(g[gid] @ lin1_w + b1) @ lin2_w + b2
// ===========================================================================
__global__ __launch_bounds__(128)
void head_kernel(const float* __restrict__ g, const float* __restrict__ w1,
                 const float* __restrict__ b1, const float* __restrict__ w2,
                 const float* __restrict__ b2, float* __restrict__ out)
{
    __shared__ float gs[DIM];
    __shared__ float red[6];
    int gid = blockIdx.x;
    int t = threadIdx.x;

    gs[t] = g[(size_t)gid * DIM + t];
    __syncthreads();

    float acc = b1[t];
#pragma unroll
    for (int k = 0; k < DIM; ++k) acc = fmaf(gs[k], w1[k * DIM + t], acc);
    float h = fmaxf(acc, 0.f);

    float c0 = h * w2[t * 3 + 0];
    float c1 = h * w2[t * 3 + 1];
    float c2 = h * w2[t * 3 + 2];
#pragma unroll
    for (int off = 32; off >= 1; off >>= 1) {
        c0 += __shfl_down(c0, off);
        c1 += __shfl_down(c1, off);
        c2 += __shfl_down(c2, off);
    }
    int wave = t >> 6;
    if ((t & 63) == 0) {
        red[wave * 3 + 0] = c0;
        red[wave * 3 + 1] = c1;
        red[wave * 3 + 2] = c2;
    }
    __syncthreads();
    if (t == 0) {
        out[(size_t)gid * 3 + 0] = red[0] + red[3] + b2[0];
        out[(size_t)gid * 3 + 1] = red[1] + red[4] + b2[1];
        out[(size_t)gid * 3 + 2] = red[2] + red[5] + b2[2];
    }
}

// ===========================================================================
extern "C" void kernel_launch(void* const* d_in, const int* in_sizes, int n_in,
                              void* d_out, int out_size, void* d_ws, size_t ws_size,
                              hipStream_t stream)
{
    const float* x       = (const float*)d_in[0];
    const int*   eidx    = (const int*)d_in[1];
    const int*   batch   = (const int*)d_in[2];
    const float* gin_w1  = (const float*)d_in[3];
    const float* gin_b1  = (const float*)d_in[4];
    const float* gin_w2  = (const float*)d_in[5];
    const float* gin_b2  = (const float*)d_in[6];
    const float* gcn_w   = (const float*)d_in[7];
    const float* gcn_b   = (const float*)d_in[8];
    const float* lin1_w  = (const float*)d_in[9];
    const float* lin1_b  = (const float*)d_in[10];
    const float* lin2_w  = (const float*)d_in[11];
    const float* lin2_b  = (const float*)d_in[12];

    const int* src = eidx;
    const int* dst = eidx + N_EDGES;

    // workspace carve (256B aligned)
    const size_t NB  = (size_t)N_NODES * DIM * sizeof(float);        // 51.2 MB
    const size_t NBH = (size_t)N_NODES * DIM * sizeof(unsigned short); // 25.6 MB
    char* base = (char*)d_ws;
    size_t off = 0;
    auto carve = [&](size_t bytes) {
        char* p = base + off;
        off = (off + bytes + 255) & ~(size_t)255;
        return p;
    };
    float*          bufA = (float*)carve(NB);            // gathered H (fp32)
    unsigned short* xb   = (unsigned short*)carve(NBH);  // x in bf16
    unsigned short* ub   = (unsigned short*)carve(NBH);  // u in bf16
    int*   cnt    = (int*)  carve(N_NODES * sizeof(int));      // cnt -> dinv
    int*   rp     = (int*)  carve((N_NODES + 1) * sizeof(int));
    int*   cursor = (int*)  carve(N_NODES * sizeof(int));
    int*   csr    = (int*)  carve((size_t)N_EDGES * sizeof(int));
    int*   bsum   = (int*)  carve(SCAN_NBLK * sizeof(int));
    float* g      = (float*)carve((size_t)N_GRAPHS * DIM * sizeof(float));
    float* dinv   = (float*)cnt;   // in-place conversion in scan3

    hipMemsetAsync(cnt, 0, N_NODES * sizeof(int), stream);
    hipMemsetAsync(g, 0, (size_t)N_GRAPHS * DIM * sizeof(float), stream);

    const int ngrid = (N_NODES + 7) / 8;
    const int mgrid = (N_NODES + MB - 1) / MB;
    const int pgrid = (N_NODES + P2_NODES - 1) / P2_NODES;

    // ---- cast x -> bf16 (independent of CSR build) ----
    cast_bf16<<<(N_NODES * DIM / 8 + 255) / 256, 256, 0, stream>>>(
        x, xb, N_NODES * DIM / 8);

    // ---- CSR build ----
    cnt_kernel<<<FILL_RANGES * 128, 256, 0, stream>>>(dst, cnt, N_EDGES);
    scan1<<<SCAN_NBLK, SCAN_T, 0, stream>>>(cnt, rp, bsum, N_NODES);
    scan2<<<1, 128, 0, stream>>>(bsum, SCAN_NBLK);
    scan3<<<(N_NODES + 256) / 256, 256, 0, stream>>>(rp, cursor, bsum, cnt,
                                                     N_NODES, N_EDGES);
    csr_fill<<<FILL_RANGES * 128, 256, 0, stream>>>(src, dst, cursor, csr, N_EDGES);

    // ---- GIN gather (bf16 source, fp32 accumulate) ----
    csr_gather_b<<<ngrid, 256, 0, stream>>>(rp, csr, xb, bufA, N_NODES);

    // ---- fused 3-layer MLP -> u (bf16) ----
    mlp3<<<mgrid, 128, 0, stream>>>(bufA, gin_w1, gin_b1, gin_w2, gin_b2,
                                    gcn_w, dinv, ub, N_NODES);

    // ---- fused GCN gather (bf16) + finalize + pool -> g ----
    gcn_gather_pool<<<pgrid, 256, 0, stream>>>(rp, csr, ub, dinv, gcn_b,
                                               batch, g, N_NODES);

    // ---- head ----
    head_kernel<<<N_GRAPHS, 128, 0, stream>>>(
        g, lin1_w, lin1_b, lin2_w, lin2_b, (float*)d_out);
}

// Round 9
// 497.205 us; speedup vs baseline: 1.3633x; 1.1379x over previous
//
#include <hip/hip_runtime.h>
#include <hip/hip_bf16.h>

// Problem constants (match reference)
#define N_NODES  100000
#define N_EDGES  1600000
#define N_GRAPHS 2048
#define DIM      128   // IN_DIM == HIDDEN == 128

// ---- bf16 helpers (RNE encode, bit-shift decode) --------------------------
__device__ __forceinline__ unsigned short f2b(float f) {
    unsigned u = __float_as_uint(f);
    u += 0x7FFFu + ((u >> 16) & 1u);
    return (unsigned short)(u >> 16);
}
__device__ __forceinline__ float b2f(unsigned short h) {
    return __uint_as_float(((unsigned)h) << 16);
}
__device__ __forceinline__ float4 dec4(ushort4 h) {
    return make_float4(b2f(h.x), b2f(h.y), b2f(h.z), b2f(h.w));
}

// MFMA fragment types (gfx950, 16x16x32 bf16: 8 bf16 in / 4 fp32 acc)
typedef __attribute__((ext_vector_type(8))) short bfrag;
typedef __attribute__((ext_vector_type(4))) float ffrag;

// ===========================================================================
// Cast fp32 -> bf16 (8 elems/thread)
// ===========================================================================
__global__ __launch_bounds__(256)
void cast_bf16(const float* __restrict__ in, unsigned short* __restrict__ out,
               int n8)
{
    int i = blockIdx.x * 256 + threadIdx.x;
    if (i >= n8) return;
    const float4* in4 = (const float4*)in;
    float4 a = in4[i * 2 + 0];
    float4 b = in4[i * 2 + 1];
    uint4 q;
    q.x = (unsigned)f2b(a.x) | ((unsigned)f2b(a.y) << 16);
    q.y = (unsigned)f2b(a.z) | ((unsigned)f2b(a.w) << 16);
    q.z = (unsigned)f2b(b.x) | ((unsigned)f2b(b.y) << 16);
    q.w = (unsigned)f2b(b.z) | ((unsigned)f2b(b.w) << 16);
    ((uint4*)out)[i] = q;
}

// Cast + transpose one 128x128 weight: Wt[n][k] = bf16(W[k][n])
__global__ __launch_bounds__(256)
void cast_tr_w(const float* __restrict__ W, unsigned short* __restrict__ Wt)
{
    int f = blockIdx.x * 256 + threadIdx.x;   // 0..16383
    int k = f >> 7, n = f & 127;
    Wt[n * DIM + k] = f2b(W[f]);
}

// ===========================================================================
// CSR construction (XCD-partitioned counting + fill)
// ===========================================================================
#define FILL_RANGES 8
#define FILL_RSIZE  (N_NODES / FILL_RANGES)   // 12500 exact

__global__ __launch_bounds__(256)
void cnt_kernel(const int* __restrict__ dst, int* __restrict__ cnt, int E)
{
    const int r = blockIdx.x & (FILL_RANGES - 1);
    const int s = blockIdx.x >> 3;
    const int nslice = gridDim.x >> 3;
    const unsigned lo = (unsigned)(r * FILL_RSIZE);
    const int stride = nslice * 256 * 4;

    for (int e0 = (s * 256 + threadIdx.x) * 4; e0 < E; e0 += stride) {
        int4 d = *(const int4*)&dst[e0];
        if ((unsigned)(d.x - lo) < (unsigned)FILL_RSIZE) atomicAdd(&cnt[d.x], 1);
        if ((unsigned)(d.y - lo) < (unsigned)FILL_RSIZE) atomicAdd(&cnt[d.y], 1);
        if ((unsigned)(d.z - lo) < (unsigned)FILL_RSIZE) atomicAdd(&cnt[d.z], 1);
        if ((unsigned)(d.w - lo) < (unsigned)FILL_RSIZE) atomicAdd(&cnt[d.w], 1);
    }
}

#define SCAN_T     256
#define SCAN_E     4
#define SCAN_CHUNK 1024   // SCAN_T * SCAN_E
#define SCAN_NBLK  ((N_NODES + SCAN_CHUNK - 1) / SCAN_CHUNK)   // 98

__global__ __launch_bounds__(SCAN_T)
void scan1(const int* __restrict__ cnt, int* __restrict__ rp,
           int* __restrict__ bsum, int N)
{
    __shared__ int sh[SCAN_T];
    int b = blockIdx.x, t = threadIdx.x;
    int base = b * SCAN_CHUNK + t * SCAN_E;
    int v[SCAN_E];
    int s = 0;
#pragma unroll
    for (int i = 0; i < SCAN_E; ++i) {
        int idx = base + i;
        v[i] = (idx < N) ? cnt[idx] : 0;
        s += v[i];
    }
    sh[t] = s;
    __syncthreads();
    for (int off = 1; off < SCAN_T; off <<= 1) {
        int add = (t >= off) ? sh[t - off] : 0;
        __syncthreads();
        sh[t] += add;
        __syncthreads();
    }
    int excl = sh[t] - s;
    if (t == SCAN_T - 1) bsum[b] = sh[t];
    int run = excl;
#pragma unroll
    for (int i = 0; i < SCAN_E; ++i) {
        int idx = base + i;
        if (idx < N) rp[idx] = run;
        run += v[i];
    }
}

__global__ __launch_bounds__(128)
void scan2(int* __restrict__ bsum, int nb)
{
    __shared__ int sh[128];
    int t = threadIdx.x;
    int v = (t < nb) ? bsum[t] : 0;
    sh[t] = v;
    __syncthreads();
    for (int off = 1; off < 128; off <<= 1) {
        int add = (t >= off) ? sh[t - off] : 0;
        __syncthreads();
        sh[t] += add;
        __syncthreads();
    }
    if (t < nb) bsum[t] = sh[t] - v;   // exclusive
}

// Phase 3: add block offsets; emit row_ptr + cursor; also cnt -> dinv (fused)
__global__ __launch_bounds__(256)
void scan3(int* __restrict__ rp, int* __restrict__ cursor,
           const int* __restrict__ bsum, int* __restrict__ cnt, int N, int E)
{
    int i = blockIdx.x * blockDim.x + threadIdx.x;
    if (i < N) {
        int v = rp[i] + bsum[i / SCAN_CHUNK];
        rp[i] = v;
        cursor[i] = v;
        float d = (float)cnt[i] + 1.0f;
        ((float*)cnt)[i] = rsqrtf(d);   // in-place: cnt buffer becomes dinv
    }
    if (i == N) rp[N] = E;
}

// XCD-partitioned fill
__global__ __launch_bounds__(256)
void csr_fill(const int* __restrict__ src, const int* __restrict__ dst,
              int* __restrict__ cursor, int* __restrict__ csr, int E)
{
    const int r = blockIdx.x & (FILL_RANGES - 1);
    const int s = blockIdx.x >> 3;
    const int nslice = gridDim.x >> 3;
    const unsigned lo = (unsigned)(r * FILL_RSIZE);
    const int stride = nslice * 256 * 4;

    for (int e0 = (s * 256 + threadIdx.x) * 4; e0 < E; e0 += stride) {
        int4 d  = *(const int4*)&dst[e0];
        int4 sv = *(const int4*)&src[e0];
        if ((unsigned)(d.x - lo) < (unsigned)FILL_RSIZE) {
            int p = atomicAdd(&cursor[d.x], 1); csr[p] = sv.x;
        }
        if ((unsigned)(d.y - lo) < (unsigned)FILL_RSIZE) {
            int p = atomicAdd(&cursor[d.y], 1); csr[p] = sv.y;
        }
        if ((unsigned)(d.z - lo) < (unsigned)FILL_RSIZE) {
            int p = atomicAdd(&cursor[d.z], 1); csr[p] = sv.z;
        }
        if ((unsigned)(d.w - lo) < (unsigned)FILL_RSIZE) {
            int p = atomicAdd(&cursor[d.w], 1); csr[p] = sv.w;
        }
    }
}

// ===========================================================================
// bf16 CSR gather -> bf16 out: Out[i] = Vb[i] + sum Vb[csr[e]] (fp32 acc)
// ===========================================================================
__global__ __launch_bounds__(256)
void csr_gather_bb(const int* __restrict__ rp, const int* __restrict__ csr,
                   const unsigned short* __restrict__ Vb,
                   unsigned short* __restrict__ Out, int N)
{
    int node = blockIdx.x * 8 + (threadIdx.x >> 5);
    int lane = threadIdx.x & 31;
    if (node >= N) return;
    int beg = rp[node];
    int end = rp[node + 1];
    const ushort4* V4 = (const ushort4*)Vb;   // 32 ushort4 per row
    float4 acc = dec4(V4[(size_t)node * 32 + lane]);   // self term
    int e = beg;
    for (; e + 4 <= end; e += 4) {
        int s0 = csr[e + 0];
        int s1 = csr[e + 1];
        int s2 = csr[e + 2];
        int s3 = csr[e + 3];
        float4 v0 = dec4(V4[(size_t)s0 * 32 + lane]);
        float4 v1 = dec4(V4[(size_t)s1 * 32 + lane]);
        float4 v2 = dec4(V4[(size_t)s2 * 32 + lane]);
        float4 v3 = dec4(V4[(size_t)s3 * 32 + lane]);
        acc.x += v0.x + v1.x + v2.x + v3.x;
        acc.y += v0.y + v1.y + v2.y + v3.y;
        acc.z += v0.z + v1.z + v2.z + v3.z;
        acc.w += v0.w + v1.w + v2.w + v3.w;
    }
    for (; e < end; ++e) {
        int s = csr[e];
        float4 v = dec4(V4[(size_t)s * 32 + lane]);
        acc.x += v.x; acc.y += v.y; acc.z += v.z; acc.w += v.w;
    }
    ushort4 o;
    o.x = f2b(acc.x); o.y = f2b(acc.y); o.z = f2b(acc.z); o.w = f2b(acc.w);
    ((ushort4*)Out)[(size_t)node * 32 + lane] = o;
}

// ===========================================================================
// Fused 3-layer MLP via MFMA 16x16x32 bf16 (fp32 accumulate):
//   L0: H = relu(H @ w1 + b1); L1: H = relu(H @ w2 + b2)
//   L2: u = dinv[row] * (H @ w3) -> global bf16
// Block = 256 thr = 4 waves; 64 rows/block; wave w owns rows w*16..w*16+15
// (row-parallel -> no inter-layer barriers). H tile bf16 in LDS, row stride
// 136 ushorts (272 B: 16B-aligned, 68 dw -> 4-bank row skew, worst 2-way).
// A-frag:  A[m=lane&15][k=quad*8+j]  (verified layout, m89/m120)
// B-frag:  B[k=quad*8+j][n=lane&15]  -> contiguous reads from Wt[n][k]
// C/D:     col=lane&15, row=quad*4+reg (verified layout, m89)
// Weights read straight from global (3x32 KB bf16, L1/L2-hot, no staging).
// ===========================================================================
#define MLP_ROWS 64
#define HBST     136

__global__ __launch_bounds__(256)
void mlp3_mfma(const unsigned short* __restrict__ Hg,
               const unsigned short* __restrict__ w1t, const float* __restrict__ b1,
               const unsigned short* __restrict__ w2t, const float* __restrict__ b2,
               const unsigned short* __restrict__ w3t, const float* __restrict__ dinv,
               unsigned short* __restrict__ ub_out, int N)
{
    __shared__ unsigned short Hb[MLP_ROWS][HBST];

    const int tid  = threadIdx.x;
    const int wave = tid >> 6;        // 0..3
    const int lane = tid & 63;
    const int row0 = blockIdx.x * MLP_ROWS;

    // ---- load H tile (coalesced uint4 = 8 bf16): 1024 x 16 B, 4/thread ----
#pragma unroll
    for (int l = 0; l < 4; ++l) {
        int f  = tid + l * 256;       // 0..1023
        int r  = f >> 4;              // 0..63
        int c8 = (f & 15) << 3;       // 0,8,...,120
        int gr = row0 + r;
        uint4 v = make_uint4(0u, 0u, 0u, 0u);
        if (gr < N) v = *(const uint4*)&Hg[(size_t)gr * DIM + c8];
        *(uint4*)&Hb[r][c8] = v;
    }
    __syncthreads();   // only barrier: loaders != owners

    const int m0 = wave * 16;
    const int qa = lane >> 4;         // quad 0..3
    const int la = lane & 15;

    for (int layer = 0; layer < 3; ++layer) {
        const unsigned short* __restrict__ Wt =
            (layer == 0) ? w1t : (layer == 1) ? w2t : w3t;

        // A fragments for this wave's 16 rows, all K (4 chunks of 32)
        bfrag afr[4];
#pragma unroll
        for (int kc = 0; kc < 4; ++kc)
            afr[kc] = *(const bfrag*)&Hb[m0 + la][kc * 32 + qa * 8];

        if (layer < 2) {
            const float* bias = (layer == 0) ? b1 : b2;
#pragma unroll
            for (int nt = 0; nt < 8; ++nt) {
                const int n0 = nt * 16;
                ffrag acc = {0.f, 0.f, 0.f, 0.f};
#pragma unroll
                for (int kc = 0; kc < 4; ++kc) {
                    bfrag bfr = *(const bfrag*)&Wt[(size_t)(n0 + la) * DIM + kc * 32 + qa * 8];
                    acc = __builtin_amdgcn_mfma_f32_16x16x32_bf16(afr[kc], bfr, acc, 0, 0, 0);
                }
                float bn = bias[n0 + la];
#pragma unroll
                for (int r = 0; r < 4; ++r) {
                    float v = fmaxf(acc[r] + bn, 0.f);
                    Hb[m0 + qa * 4 + r][n0 + la] = f2b(v);
                }
            }
            // wave-private rows: program order + compiler waitcnt suffice
        } else {
            float dv[4];
#pragma unroll
            for (int r = 0; r < 4; ++r) {
                int gr = row0 + m0 + qa * 4 + r;
                dv[r] = (gr < N) ? dinv[gr] : 0.f;
            }
#pragma unroll
            for (int nt = 0; nt < 8; ++nt) {
                const int n0 = nt * 16;
                ffrag acc = {0.f, 0.f, 0.f, 0.f};
#pragma unroll
                for (int kc = 0; kc < 4; ++kc) {
                    bfrag bfr = *(const bfrag*)&Wt[(size_t)(n0 + la) * DIM + kc * 32 + qa * 8];
                    acc = __builtin_amdgcn_mfma_f32_16x16x32_bf16(afr[kc], bfr, acc, 0, 0, 0);
                }
#pragma unroll
                for (int r = 0; r < 4; ++r) {
                    int gr = row0 + m0 + qa * 4 + r;
                    if (gr < N)
                        ub_out[(size_t)gr * DIM + n0 + la] = f2b(dv[r] * acc[r]);
                }
            }
        }
    }
}

// ===========================================================================
// Fused GCN gather (bf16 u) + finalize + global_add_pool:
//   h_i = relu(dinv_i * (u_i + sum u[csr]) + b);  g[batch[i]] += h_i
// ===========================================================================
#define P2_NODES 64
__global__ __launch_bounds__(256)
void gcn_gather_pool(const int* __restrict__ rp, const int* __restrict__ csr,
                     const unsigned short* __restrict__ ub,
                     const float* __restrict__ dinv,
                     const float* __restrict__ bias, const int* __restrict__ batch,
                     float* __restrict__ g, int N)
{
    const int grp  = threadIdx.x >> 5;
    const int lane = threadIdx.x & 31;
    const int n0   = blockIdx.x * P2_NODES + grp * 8;
    const ushort4* V4 = (const ushort4*)ub;

    float4 bj;
    bj.x = bias[lane * 4 + 0];
    bj.y = bias[lane * 4 + 1];
    bj.z = bias[lane * 4 + 2];
    bj.w = bias[lane * 4 + 3];

    float4 lsum = make_float4(0.f, 0.f, 0.f, 0.f);
    int prev = -1;

    for (int k = 0; k < 8; ++k) {
        int node = n0 + k;
        if (node >= N) break;
        float4 acc = dec4(V4[(size_t)node * 32 + lane]);   // self term u_i
        int e = rp[node], end = rp[node + 1];
        for (; e + 4 <= end; e += 4) {
            int s0 = csr[e + 0], s1 = csr[e + 1];
            int s2 = csr[e + 2], s3 = csr[e + 3];
            float4 v0 = dec4(V4[(size_t)s0 * 32 + lane]);
            float4 v1 = dec4(V4[(size_t)s1 * 32 + lane]);
            float4 v2 = dec4(V4[(size_t)s2 * 32 + lane]);
            float4 v3 = dec4(V4[(size_t)s3 * 32 + lane]);
            acc.x += v0.x + v1.x + v2.x + v3.x;
            acc.y += v0.y + v1.y + v2.y + v3.y;
            acc.z += v0.z + v1.z + v2.z + v3.z;
            acc.w += v0.w + v1.w + v2.w + v3.w;
        }
        for (; e < end; ++e) {
            int s = csr[e];
            float4 v = dec4(V4[(size_t)s * 32 + lane]);
            acc.x += v.x; acc.y += v.y; acc.z += v.z; acc.w += v.w;
        }
        float di = dinv[node];
        float4 h;
        h.x = fmaxf(fmaf(di, acc.x, bj.x), 0.f);
        h.y = fmaxf(fmaf(di, acc.y, bj.y), 0.f);
        h.z = fmaxf(fmaf(di, acc.z, bj.z), 0.f);
        h.w = fmaxf(fmaf(di, acc.w, bj.w), 0.f);

        int b = batch[node];
        if (b != prev) {
            if (prev >= 0) {
                float* gp = &g[(size_t)prev * DIM + lane * 4];
                atomicAdd(gp + 0, lsum.x);
                atomicAdd(gp + 1, lsum.y);
                atomicAdd(gp + 2, lsum.z);
                atomicAdd(gp + 3, lsum.w);
            }
            lsum = make_float4(0.f, 0.f, 0.f, 0.f);
            prev = b;
        }
        lsum.x += h.x; lsum.y += h.y; lsum.z += h.z; lsum.w += h.w;
    }
    if (prev >= 0) {
        float* gp = &g[(size_t)prev * DIM + lane * 4];
        atomicAdd(gp + 0, lsum.x);
        atomicAdd(gp + 1, lsum.y);
        atomicAdd(gp + 2, lsum.z);
        atomicAdd(gp + 3, lsum.w);
    }
}

// ===========================================================================
// Head: out[gid] = relu(g[gid] @ lin1_w + b1) @ lin2_w + b2
// ===========================================================================
__global__ __launch_bounds__(128)
void head_kernel(const float* __restrict__ g, const float* __restrict__ w1,
                 const float* __restrict__ b1, const float* __restrict__ w2,
                 const float* __restrict__ b2, float* __restrict__ out)
{
    __shared__ float gs[DIM];
    __shared__ float red[6];
    int gid = blockIdx.x;
    int t = threadIdx.x;

    gs[t] = g[(size_t)gid * DIM + t];
    __syncthreads();

    float acc = b1[t];
#pragma unroll
    for (int k = 0; k < DIM; ++k) acc = fmaf(gs[k], w1[k * DIM + t], acc);
    float h = fmaxf(acc, 0.f);

    float c0 = h * w2[t * 3 + 0];
    float c1 = h * w2[t * 3 + 1];
    float c2 = h * w2[t * 3 + 2];
#pragma unroll
    for (int off = 32; off >= 1; off >>= 1) {
        c0 += __shfl_down(c0, off);
        c1 += __shfl_down(c1, off);
        c2 += __shfl_down(c2, off);
    }
    int wave = t >> 6;
    if ((t & 63) == 0) {
        red[wave * 3 + 0] = c0;
        red[wave * 3 + 1] = c1;
        red[wave * 3 + 2] = c2;
    }
    __syncthreads();
    if (t == 0) {
        out[(size_t)gid * 3 + 0] = red[0] + red[3] + b2[0];
        out[(size_t)gid * 3 + 1] = red[1] + red[4] + b2[1];
        out[(size_t)gid * 3 + 2] = red[2] + red[5] + b2[2];
    }
}

// ===========================================================================
extern "C" void kernel_launch(void* const* d_in, const int* in_sizes, int n_in,
                              void* d_out, int out_size, void* d_ws, size_t ws_size,
                              hipStream_t stream)
{
    const float* x       = (const float*)d_in[0];
    const int*   eidx    = (const int*)d_in[1];
    const int*   batch   = (const int*)d_in[2];
    const float* gin_w1  = (const float*)d_in[3];
    const float* gin_b1  = (const float*)d_in[4];
    const float* gin_w2  = (const float*)d_in[5];
    const float* gin_b2  = (const float*)d_in[6];
    const float* gcn_w   = (const float*)d_in[7];
    const float* gcn_b   = (const float*)d_in[8];
    const float* lin1_w  = (const float*)d_in[9];
    const float* lin1_b  = (const float*)d_in[10];
    const float* lin2_w  = (const float*)d_in[11];
    const float* lin2_b  = (const float*)d_in[12];

    const int* src = eidx;
    const int* dst = eidx + N_EDGES;

    // workspace carve (256B aligned)
    const size_t NBH = (size_t)N_NODES * DIM * sizeof(unsigned short); // 25.6 MB
    const size_t WTB = (size_t)DIM * DIM * sizeof(unsigned short);     // 32 KB
    char* base = (char*)d_ws;
    size_t off = 0;
    auto carve = [&](size_t bytes) {
        char* p = base + off;
        off = (off + bytes + 255) & ~(size_t)255;
        return p;
    };
    unsigned short* xb  = (unsigned short*)carve(NBH);  // x in bf16
    unsigned short* hb  = (unsigned short*)carve(NBH);  // gathered H in bf16
    unsigned short* ub  = (unsigned short*)carve(NBH);  // u in bf16
    unsigned short* w1t = (unsigned short*)carve(WTB);  // gin_w1^T bf16
    unsigned short* w2t = (unsigned short*)carve(WTB);
    unsigned short* w3t = (unsigned short*)carve(WTB);
    int*   cnt    = (int*)  carve(N_NODES * sizeof(int));      // cnt -> dinv
    int*   rp     = (int*)  carve((N_NODES + 1) * sizeof(int));
    int*   cursor = (int*)  carve(N_NODES * sizeof(int));
    int*   csr    = (int*)  carve((size_t)N_EDGES * sizeof(int));
    int*   bsum   = (int*)  carve(SCAN_NBLK * sizeof(int));
    float* g      = (float*)carve((size_t)N_GRAPHS * DIM * sizeof(float));
    float* dinv   = (float*)cnt;   // in-place conversion in scan3

    hipMemsetAsync(cnt, 0, N_NODES * sizeof(int), stream);
    hipMemsetAsync(g, 0, (size_t)N_GRAPHS * DIM * sizeof(float), stream);

    const int ngrid = (N_NODES + 7) / 8;
    const int mgrid = (N_NODES + MLP_ROWS - 1) / MLP_ROWS;
    const int pgrid = (N_NODES + P2_NODES - 1) / P2_NODES;

    // ---- casts (independent of CSR build) ----
    cast_bf16<<<(N_NODES * DIM / 8 + 255) / 256, 256, 0, stream>>>(
        x, xb, N_NODES * DIM / 8);
    cast_tr_w<<<DIM * DIM / 256, 256, 0, stream>>>(gin_w1, w1t);
    cast_tr_w<<<DIM * DIM / 256, 256, 0, stream>>>(gin_w2, w2t);
    cast_tr_w<<<DIM * DIM / 256, 256, 0, stream>>>(gcn_w,  w3t);

    // ---- CSR build ----
    cnt_kernel<<<FILL_RANGES * 128, 256, 0, stream>>>(dst, cnt, N_EDGES);
    scan1<<<SCAN_NBLK, SCAN_T, 0, stream>>>(cnt, rp, bsum, N_NODES);
    scan2<<<1, 128, 0, stream>>>(bsum, SCAN_NBLK);
    scan3<<<(N_NODES + 256) / 256, 256, 0, stream>>>(rp, cursor, bsum, cnt,
                                                     N_NODES, N_EDGES);
    csr_fill<<<FILL_RANGES * 128, 256, 0, stream>>>(src, dst, cursor, csr, N_EDGES);

    // ---- GIN gather (bf16 in/out, fp32 accumulate) ----
    csr_gather_bb<<<ngrid, 256, 0, stream>>>(rp, csr, xb, hb, N_NODES);

    // ---- fused 3-layer MLP via MFMA -> u (bf16) ----
    mlp3_mfma<<<mgrid, 256, 0, stream>>>(hb, w1t, gin_b1, w2t, gin_b2,
                                         w3t, dinv, ub, N_NODES);

    // ---- fused GCN gather (bf16) + finalize + pool -> g ----
    gcn_gather_pool<<<pgrid, 256, 0, stream>>>(rp, csr, ub, dinv, gcn_b,
                                               batch, g, N_NODES);

    // ---- head ----
    head_kernel<<<N_GRAPHS, 128, 0, stream>>>(
        g, lin1_w, lin1_b, lin2_w, lin2_b, (float*)d_out);
}

// Round 10
// 441.993 us; speedup vs baseline: 1.5336x; 1.1249x over previous
//
#include <hip/hip_runtime.h>
#include <hip/hip_bf16.h>

// Problem constants (match reference)
#define N_NODES  100000
#define N_EDGES  1600000
#define N_GRAPHS 2048
#define DIM      128   // IN_DIM == HIDDEN == 128

// ---- bf16 helpers (RNE encode, bit-shift decode) --------------------------
__device__ __forceinline__ unsigned short f2b(float f) {
    unsigned u = __float_as_uint(f);
    u += 0x7FFFu + ((u >> 16) & 1u);
    return (unsigned short)(u >> 16);
}
__device__ __forceinline__ float b2f(unsigned short h) {
    return __uint_as_float(((unsigned)h) << 16);
}
__device__ __forceinline__ float4 dec4(ushort4 h) {
    return make_float4(b2f(h.x), b2f(h.y), b2f(h.z), b2f(h.w));
}

// MFMA fragment types (gfx950, 16x16x32 bf16: 8 bf16 in / 4 fp32 acc)
typedef __attribute__((ext_vector_type(8))) short bfrag;
typedef __attribute__((ext_vector_type(4))) float ffrag;

// ===========================================================================
// Cast fp32 -> bf16 (8 elems/thread). Also zeroes cnt[] (runs first in the
// stream; its 1.6M threads cover N_NODES) -- replaces a hipMemsetAsync.
// ===========================================================================
__global__ __launch_bounds__(256)
void cast_bf16(const float* __restrict__ in, unsigned short* __restrict__ out,
               int* __restrict__ cnt, int n8)
{
    int i = blockIdx.x * 256 + threadIdx.x;
    if (i < N_NODES) cnt[i] = 0;
    if (i >= n8) return;
    const float4* in4 = (const float4*)in;
    float4 a = in4[i * 2 + 0];
    float4 b = in4[i * 2 + 1];
    uint4 q;
    q.x = (unsigned)f2b(a.x) | ((unsigned)f2b(a.y) << 16);
    q.y = (unsigned)f2b(a.z) | ((unsigned)f2b(a.w) << 16);
    q.z = (unsigned)f2b(b.x) | ((unsigned)f2b(b.y) << 16);
    q.w = (unsigned)f2b(b.z) | ((unsigned)f2b(b.w) << 16);
    ((uint4*)out)[i] = q;
}

// Cast + transpose all 3 weights in one launch: Wt[n][k] = bf16(W[k][n])
// grid = 3 * 64 blocks; blockIdx/64 selects the weight.
__global__ __launch_bounds__(256)
void cast_tr_w3(const float* __restrict__ Wa, unsigned short* __restrict__ Ta,
                const float* __restrict__ Wb, unsigned short* __restrict__ Tb,
                const float* __restrict__ Wc, unsigned short* __restrict__ Tc)
{
    int which = blockIdx.x >> 6;
    int f = (blockIdx.x & 63) * 256 + threadIdx.x;   // 0..16383
    const float* W = (which == 0) ? Wa : (which == 1) ? Wb : Wc;
    unsigned short* T = (which == 0) ? Ta : (which == 1) ? Tb : Tc;
    int k = f >> 7, n = f & 127;
    T[n * DIM + k] = f2b(W[f]);
}

// ===========================================================================
// CSR construction (XCD-partitioned counting + fill)
// ===========================================================================
#define FILL_RANGES 8
#define FILL_RSIZE  (N_NODES / FILL_RANGES)   // 12500 exact

// Also zeroes g[] (1024 blocks x 256 = exactly N_GRAPHS*DIM) -- replaces a
// hipMemsetAsync; pool atomics run much later in stream order.
__global__ __launch_bounds__(256)
void cnt_kernel(const int* __restrict__ dst, int* __restrict__ cnt,
                float* __restrict__ g, int E)
{
    int gid = blockIdx.x * 256 + threadIdx.x;   // < 262144 == N_GRAPHS*DIM
    g[gid] = 0.f;

    const int r = blockIdx.x & (FILL_RANGES - 1);
    const int s = blockIdx.x >> 3;
    const int nslice = gridDim.x >> 3;
    const unsigned lo = (unsigned)(r * FILL_RSIZE);
    const int stride = nslice * 256 * 4;

    for (int e0 = (s * 256 + threadIdx.x) * 4; e0 < E; e0 += stride) {
        int4 d = *(const int4*)&dst[e0];
        if ((unsigned)(d.x - lo) < (unsigned)FILL_RSIZE) atomicAdd(&cnt[d.x], 1);
        if ((unsigned)(d.y - lo) < (unsigned)FILL_RSIZE) atomicAdd(&cnt[d.y], 1);
        if ((unsigned)(d.z - lo) < (unsigned)FILL_RSIZE) atomicAdd(&cnt[d.z], 1);
        if ((unsigned)(d.w - lo) < (unsigned)FILL_RSIZE) atomicAdd(&cnt[d.w], 1);
    }
}

#define SCAN_T     256
#define SCAN_E     4
#define SCAN_CHUNK 1024   // SCAN_T * SCAN_E
#define SCAN_NBLK  ((N_NODES + SCAN_CHUNK - 1) / SCAN_CHUNK)   // 98

__global__ __launch_bounds__(SCAN_T)
void scan1(const int* __restrict__ cnt, int* __restrict__ rp,
           int* __restrict__ bsum, int N)
{
    __shared__ int sh[SCAN_T];
    int b = blockIdx.x, t = threadIdx.x;
    int base = b * SCAN_CHUNK + t * SCAN_E;
    int v[SCAN_E];
    int s = 0;
#pragma unroll
    for (int i = 0; i < SCAN_E; ++i) {
        int idx = base + i;
        v[i] = (idx < N) ? cnt[idx] : 0;
        s += v[i];
    }
    sh[t] = s;
    __syncthreads();
    for (int off = 1; off < SCAN_T; off <<= 1) {
        int add = (t >= off) ? sh[t - off] : 0;
        __syncthreads();
        sh[t] += add;
        __syncthreads();
    }
    int excl = sh[t] - s;
    if (t == SCAN_T - 1) bsum[b] = sh[t];
    int run = excl;
#pragma unroll
    for (int i = 0; i < SCAN_E; ++i) {
        int idx = base + i;
        if (idx < N) rp[idx] = run;
        run += v[i];
    }
}

__global__ __launch_bounds__(128)
void scan2(int* __restrict__ bsum, int nb)
{
    __shared__ int sh[128];
    int t = threadIdx.x;
    int v = (t < nb) ? bsum[t] : 0;
    sh[t] = v;
    __syncthreads();
    for (int off = 1; off < 128; off <<= 1) {
        int add = (t >= off) ? sh[t - off] : 0;
        __syncthreads();
        sh[t] += add;
        __syncthreads();
    }
    if (t < nb) bsum[t] = sh[t] - v;   // exclusive
}

// Phase 3: add block offsets; emit row_ptr + cursor; also cnt -> dinv (fused)
__global__ __launch_bounds__(256)
void scan3(int* __restrict__ rp, int* __restrict__ cursor,
           const int* __restrict__ bsum, int* __restrict__ cnt, int N, int E)
{
    int i = blockIdx.x * blockDim.x + threadIdx.x;
    if (i < N) {
        int v = rp[i] + bsum[i / SCAN_CHUNK];
        rp[i] = v;
        cursor[i] = v;
        float d = (float)cnt[i] + 1.0f;
        ((float*)cnt)[i] = rsqrtf(d);   // in-place: cnt buffer becomes dinv
    }
    if (i == N) rp[N] = E;
}

// XCD-partitioned fill
__global__ __launch_bounds__(256)
void csr_fill(const int* __restrict__ src, const int* __restrict__ dst,
              int* __restrict__ cursor, int* __restrict__ csr, int E)
{
    const int r = blockIdx.x & (FILL_RANGES - 1);
    const int s = blockIdx.x >> 3;
    const int nslice = gridDim.x >> 3;
    const unsigned lo = (unsigned)(r * FILL_RSIZE);
    const int stride = nslice * 256 * 4;

    for (int e0 = (s * 256 + threadIdx.x) * 4; e0 < E; e0 += stride) {
        int4 d  = *(const int4*)&dst[e0];
        int4 sv = *(const int4*)&src[e0];
        if ((unsigned)(d.x - lo) < (unsigned)FILL_RSIZE) {
            int p = atomicAdd(&cursor[d.x], 1); csr[p] = sv.x;
        }
        if ((unsigned)(d.y - lo) < (unsigned)FILL_RSIZE) {
            int p = atomicAdd(&cursor[d.y], 1); csr[p] = sv.y;
        }
        if ((unsigned)(d.z - lo) < (unsigned)FILL_RSIZE) {
            int p = atomicAdd(&cursor[d.z], 1); csr[p] = sv.z;
        }
        if ((unsigned)(d.w - lo) < (unsigned)FILL_RSIZE) {
            int p = atomicAdd(&cursor[d.w], 1); csr[p] = sv.w;
        }
    }
}

// ===========================================================================
// bf16 CSR gather -> bf16 out: Out[i] = Vb[i] + sum Vb[csr[e]] (fp32 acc)
// ===========================================================================
__global__ __launch_bounds__(256)
void csr_gather_bb(const int* __restrict__ rp, const int* __restrict__ csr,
                   const unsigned short* __restrict__ Vb,
                   unsigned short* __restrict__ Out, int N)
{
    int node = blockIdx.x * 8 + (threadIdx.x >> 5);
    int lane = threadIdx.x & 31;
    if (node >= N) return;
    int beg = rp[node];
    int end = rp[node + 1];
    const ushort4* V4 = (const ushort4*)Vb;   // 32 ushort4 per row
    float4 acc = dec4(V4[(size_t)node * 32 + lane]);   // self term
    int e = beg;
    for (; e + 4 <= end; e += 4) {
        int s0 = csr[e + 0];
        int s1 = csr[e + 1];
        int s2 = csr[e + 2];
        int s3 = csr[e + 3];
        float4 v0 = dec4(V4[(size_t)s0 * 32 + lane]);
        float4 v1 = dec4(V4[(size_t)s1 * 32 + lane]);
        float4 v2 = dec4(V4[(size_t)s2 * 32 + lane]);
        float4 v3 = dec4(V4[(size_t)s3 * 32 + lane]);
        acc.x += v0.x + v1.x + v2.x + v3.x;
        acc.y += v0.y + v1.y + v2.y + v3.y;
        acc.z += v0.z + v1.z + v2.z + v3.z;
        acc.w += v0.w + v1.w + v2.w + v3.w;
    }
    for (; e < end; ++e) {
        int s = csr[e];
        float4 v = dec4(V4[(size_t)s * 32 + lane]);
        acc.x += v.x; acc.y += v.y; acc.z += v.z; acc.w += v.w;
    }
    ushort4 o;
    o.x = f2b(acc.x); o.y = f2b(acc.y); o.z = f2b(acc.z); o.w = f2b(acc.w);
    ((ushort4*)Out)[(size_t)node * 32 + lane] = o;
}

// ===========================================================================
// Fused 3-layer MLP via MFMA 16x16x32 bf16 (fp32 accumulate), v2:
// weights staged per-layer in LDS (batched ds_read_b128 replaces serialized
// L2-latency global b-frag loads -- round-9 bottleneck).
//   L0: H = relu(H @ w1 + b1); L1: H = relu(H @ w2 + b2)
//   L2: u = dinv[row] * (H @ w3) -> global bf16
// Block = 256 thr = 4 waves; 64 rows; wave w owns rows w*16..w*16+15
// (row-parallel: H writeback needs no barrier; Ws restage needs 2/layer).
// LDS: Hb 64x136 us (17.4K) + Ws 128x136 us (34.8K) = 52.2K -> 3 blocks/CU.
// A-frag:  A[m=lane&15][k=quad*8+j]; B-frag: B[k=quad*8+j][n=lane&15] from
// Ws[n][k]; C/D: col=lane&15, row=quad*4+reg (verified layouts, m89/m120).
// ===========================================================================
#define MLP_ROWS 64
#define HBST     136

__global__ __launch_bounds__(256)
void mlp3_mfma(const unsigned short* __restrict__ Hg,
               const unsigned short* __restrict__ w1t, const float* __restrict__ b1,
               const unsigned short* __restrict__ w2t, const float* __restrict__ b2,
               const unsigned short* __restrict__ w3t, const float* __restrict__ dinv,
               unsigned short* __restrict__ ub_out, int N)
{
    __shared__ unsigned short Hb[MLP_ROWS][HBST];
    __shared__ unsigned short Ws[DIM][HBST];

    const int tid  = threadIdx.x;
    const int wave = tid >> 6;        // 0..3
    const int lane = tid & 63;
    const int row0 = blockIdx.x * MLP_ROWS;

    // ---- load H tile (coalesced uint4 = 8 bf16): 1024 x 16 B, 4/thread ----
#pragma unroll
    for (int l = 0; l < 4; ++l) {
        int f  = tid + l * 256;       // 0..1023
        int r  = f >> 4;              // 0..63
        int c8 = (f & 15) << 3;       // 0,8,...,120
        int gr = row0 + r;
        uint4 v = make_uint4(0u, 0u, 0u, 0u);
        if (gr < N) v = *(const uint4*)&Hg[(size_t)gr * DIM + c8];
        *(uint4*)&Hb[r][c8] = v;
    }

    const int m0 = wave * 16;
    const int qa = lane >> 4;         // quad 0..3
    const int la = lane & 15;

    for (int layer = 0; layer < 3; ++layer) {
        const unsigned short* __restrict__ Wt =
            (layer == 0) ? w1t : (layer == 1) ? w2t : w3t;

        // ---- stage Wt[128][128] -> Ws: 2048 uint4, 8/thread (L2-hot) ----
        __syncthreads();   // prior-layer Ws reads (and layer-0 H load) done
#pragma unroll
        for (int l = 0; l < 8; ++l) {
            int f  = tid + l * 256;   // 0..2047
            int r  = f >> 4;          // 0..127
            int c8 = (f & 15) << 3;
            *(uint4*)&Ws[r][c8] = *(const uint4*)&Wt[(size_t)r * DIM + c8];
        }
        __syncthreads();

        // A fragments for this wave's 16 rows, all K (4 chunks of 32)
        bfrag afr[4];
#pragma unroll
        for (int kc = 0; kc < 4; ++kc)
            afr[kc] = *(const bfrag*)&Hb[m0 + la][kc * 32 + qa * 8];

        if (layer < 2) {
            const float* bias = (layer == 0) ? b1 : b2;
#pragma unroll
            for (int nt = 0; nt < 8; ++nt) {
                const int n0 = nt * 16;
                ffrag acc = {0.f, 0.f, 0.f, 0.f};
#pragma unroll
                for (int kc = 0; kc < 4; ++kc) {
                    bfrag bfr = *(const bfrag*)&Ws[n0 + la][kc * 32 + qa * 8];
                    acc = __builtin_amdgcn_mfma_f32_16x16x32_bf16(afr[kc], bfr, acc, 0, 0, 0);
                }
                float bn = bias[n0 + la];
#pragma unroll
                for (int r = 0; r < 4; ++r) {
                    float v = fmaxf(acc[r] + bn, 0.f);
                    Hb[m0 + qa * 4 + r][n0 + la] = f2b(v);
                }
            }
            // wave-private rows: program order suffices before next layer
        } else {
            float dv[4];
#pragma unroll
            for (int r = 0; r < 4; ++r) {
                int gr = row0 + m0 + qa * 4 + r;
                dv[r] = (gr < N) ? dinv[gr] : 0.f;
            }
#pragma unroll
            for (int nt = 0; nt < 8; ++nt) {
                const int n0 = nt * 16;
                ffrag acc = {0.f, 0.f, 0.f, 0.f};
#pragma unroll
                for (int kc = 0; kc < 4; ++kc) {
                    bfrag bfr = *(const bfrag*)&Ws[n0 + la][kc * 32 + qa * 8];
                    acc = __builtin_amdgcn_mfma_f32_16x16x32_bf16(afr[kc], bfr, acc, 0, 0, 0);
                }
#pragma unroll
                for (int r = 0; r < 4; ++r) {
                    int gr = row0 + m0 + qa * 4 + r;
                    if (gr < N)
                        ub_out[(size_t)gr * DIM + n0 + la] = f2b(dv[r] * acc[r]);
                }
            }
        }
    }
}

// ===========================================================================
// Fused GCN gather (bf16 u) + finalize + global_add_pool:
//   h_i = relu(dinv_i * (u_i + sum u[csr]) + b);  g[batch[i]] += h_i
// ===========================================================================
#define P2_NODES 64
__global__ __launch_bounds__(256)
void gcn_gather_pool(const int* __restrict__ rp, const int* __restrict__ csr,
                     const unsigned short* __restrict__ ub,
                     const float* __restrict__ dinv,
                     const float* __restrict__ bias, const int* __restrict__ batch,
                     float* __restrict__ g, int N)
{
    const int grp  = threadIdx.x >> 5;
    const int lane = threadIdx.x & 31;
    const int n0   = blockIdx.x * P2_NODES + grp * 8;
    const ushort4* V4 = (const ushort4*)ub;

    float4 bj;
    bj.x = bias[lane * 4 + 0];
    bj.y = bias[lane * 4 + 1];
    bj.z = bias[lane * 4 + 2];
    bj.w = bias[lane * 4 + 3];

    float4 lsum = make_float4(0.f, 0.f, 0.f, 0.f);
    int prev = -1;

    for (int k = 0; k < 8; ++k) {
        int node = n0 + k;
        if (node >= N) break;
        float4 acc = dec4(V4[(size_t)node * 32 + lane]);   // self term u_i
        int e = rp[node], end = rp[node + 1];
        for (; e + 4 <= end; e += 4) {
            int s0 = csr[e + 0], s1 = csr[e + 1];
            int s2 = csr[e + 2], s3 = csr[e + 3];
            float4 v0 = dec4(V4[(size_t)s0 * 32 + lane]);
            float4 v1 = dec4(V4[(size_t)s1 * 32 + lane]);
            float4 v2 = dec4(V4[(size_t)s2 * 32 + lane]);
            float4 v3 = dec4(V4[(size_t)s3 * 32 + lane]);
            acc.x += v0.x + v1.x + v2.x + v3.x;
            acc.y += v0.y + v1.y + v2.y + v3.y;
            acc.z += v0.z + v1.z + v2.z + v3.z;
            acc.w += v0.w + v1.w + v2.w + v3.w;
        }
        for (; e < end; ++e) {
            int s = csr[e];
            float4 v = dec4(V4[(size_t)s * 32 + lane]);
            acc.x += v.x; acc.y += v.y; acc.z += v.z; acc.w += v.w;
        }
        float di = dinv[node];
        float4 h;
        h.x = fmaxf(fmaf(di, acc.x, bj.x), 0.f);
        h.y = fmaxf(fmaf(di, acc.y, bj.y), 0.f);
        h.z = fmaxf(fmaf(di, acc.z, bj.z), 0.f);
        h.w = fmaxf(fmaf(di, acc.w, bj.w), 0.f);

        int b = batch[node];
        if (b != prev) {
            if (prev >= 0) {
                float* gp = &g[(size_t)prev * DIM + lane * 4];
                atomicAdd(gp + 0, lsum.x);
                atomicAdd(gp + 1, lsum.y);
                atomicAdd(gp + 2, lsum.z);
                atomicAdd(gp + 3, lsum.w);
            }
            lsum = make_float4(0.f, 0.f, 0.f, 0.f);
            prev = b;
        }
        lsum.x += h.x; lsum.y += h.y; lsum.z += h.z; lsum.w += h.w;
    }
    if (prev >= 0) {
        float* gp = &g[(size_t)prev * DIM + lane * 4];
        atomicAdd(gp + 0, lsum.x);
        atomicAdd(gp + 1, lsum.y);
        atomicAdd(gp + 2, lsum.z);
        atomicAdd(gp + 3, lsum.w);
    }
}

// ===========================================================================
// Head: out[gid] = relu(g[gid] @ lin1_w + b1) @ lin2_w + b2
// ===========================================================================
__global__ __launch_bounds__(128)
void head_kernel(const float* __restrict__ g, const float* __restrict__ w1,
                 const float* __restrict__ b1, const float* __restrict__ w2,
                 const float* __restrict__ b2, float* __restrict__ out)
{
    __shared__ float gs[DIM];
    __shared__ float red[6];
    int gid = blockIdx.x;
    int t = threadIdx.x;

    gs[t] = g[(size_t)gid * DIM + t];
    __syncthreads();

    float acc = b1[t];
#pragma unroll
    for (int k = 0; k < DIM; ++k) acc = fmaf(gs[k], w1[k * DIM + t], acc);
    float h = fmaxf(acc, 0.f);

    float c0 = h * w2[t * 3 + 0];
    float c1 = h * w2[t * 3 + 1];
    float c2 = h * w2[t * 3 + 2];
#pragma unroll
    for (int off = 32; off >= 1; off >>= 1) {
        c0 += __shfl_down(c0, off);
        c1 += __shfl_down(c1, off);
        c2 += __shfl_down(c2, off);
    }
    int wave = t >> 6;
    if ((t & 63) == 0) {
        red[wave * 3 + 0] = c0;
        red[wave * 3 + 1] = c1;
        red[wave * 3 + 2] = c2;
    }
    __syncthreads();
    if (t == 0) {
        out[(size_t)gid * 3 + 0] = red[0] + red[3] + b2[0];
        out[(size_t)gid * 3 + 1] = red[1] + red[4] + b2[1];
        out[(size_t)gid * 3 + 2] = red[2] + red[5] + b2[2];
    }
}

// ===========================================================================
extern "C" void kernel_launch(void* const* d_in, const int* in_sizes, int n_in,
                              void* d_out, int out_size, void* d_ws, size_t ws_size,
                              hipStream_t stream)
{
    const float* x       = (const float*)d_in[0];
    const int*   eidx    = (const int*)d_in[1];
    const int*   batch   = (const int*)d_in[2];
    const float* gin_w1  = (const float*)d_in[3];
    const float* gin_b1  = (const float*)d_in[4];
    const float* gin_w2  = (const float*)d_in[5];
    const float* gin_b2  = (const float*)d_in[6];
    const float* gcn_w   = (const float*)d_in[7];
    const float* gcn_b   = (const float*)d_in[8];
    const float* lin1_w  = (const float*)d_in[9];
    const float* lin1_b  = (const float*)d_in[10];
    const float* lin2_w  = (const float*)d_in[11];
    const float* lin2_b  = (const float*)d_in[12];

    const int* src = eidx;
    const int* dst = eidx + N_EDGES;

    // workspace carve (256B aligned)
    const size_t NBH = (size_t)N_NODES * DIM * sizeof(unsigned short); // 25.6 MB
    const size_t WTB = (size_t)DIM * DIM * sizeof(unsigned short);     // 32 KB
    char* base = (char*)d_ws;
    size_t off = 0;
    auto carve = [&](size_t bytes) {
        char* p = base + off;
        off = (off + bytes + 255) & ~(size_t)255;
        return p;
    };
    unsigned short* xb  = (unsigned short*)carve(NBH);  // x in bf16
    unsigned short* hb  = (unsigned short*)carve(NBH);  // gathered H in bf16
    unsigned short* ub  = (unsigned short*)carve(NBH);  // u in bf16
    unsigned short* w1t = (unsigned short*)carve(WTB);  // gin_w1^T bf16
    unsigned short* w2t = (unsigned short*)carve(WTB);
    unsigned short* w3t = (unsigned short*)carve(WTB);
    int*   cnt    = (int*)  carve(N_NODES * sizeof(int));      // cnt -> dinv
    int*   rp     = (int*)  carve((N_NODES + 1) * sizeof(int));
    int*   cursor = (int*)  carve(N_NODES * sizeof(int));
    int*   csr    = (int*)  carve((size_t)N_EDGES * sizeof(int));
    int*   bsum   = (int*)  carve(SCAN_NBLK * sizeof(int));
    float* g      = (float*)carve((size_t)N_GRAPHS * DIM * sizeof(float));
    float* dinv   = (float*)cnt;   // in-place conversion in scan3

    const int ngrid = (N_NODES + 7) / 8;
    const int mgrid = (N_NODES + MLP_ROWS - 1) / MLP_ROWS;
    const int pgrid = (N_NODES + P2_NODES - 1) / P2_NODES;

    // ---- casts (also zeroes cnt) ----
    cast_bf16<<<(N_NODES * DIM / 8 + 255) / 256, 256, 0, stream>>>(
        x, xb, cnt, N_NODES * DIM / 8);
    cast_tr_w3<<<3 * 64, 256, 0, stream>>>(gin_w1, w1t, gin_w2, w2t, gcn_w, w3t);

    // ---- CSR build (cnt_kernel also zeroes g) ----
    cnt_kernel<<<FILL_RANGES * 128, 256, 0, stream>>>(dst, cnt, g, N_EDGES);
    scan1<<<SCAN_NBLK, SCAN_T, 0, stream>>>(cnt, rp, bsum, N_NODES);
    scan2<<<1, 128, 0, stream>>>(bsum, SCAN_NBLK);
    scan3<<<(N_NODES + 256) / 256, 256, 0, stream>>>(rp, cursor, bsum, cnt,
                                                     N_NODES, N_EDGES);
    csr_fill<<<FILL_RANGES * 128, 256, 0, stream>>>(src, dst, cursor, csr, N_EDGES);

    // ---- GIN gather (bf16 in/out, fp32 accumulate) ----
    csr_gather_bb<<<ngrid, 256, 0, stream>>>(rp, csr, xb, hb, N_NODES);

    // ---- fused 3-layer MLP via MFMA (W staged in LDS) -> u (bf16) ----
    mlp3_mfma<<<mgrid, 256, 0, stream>>>(hb, w1t, gin_b1, w2t, gin_b2,
                                         w3t, dinv, ub, N_NODES);

    // ---- fused GCN gather (bf16) + finalize + pool -> g ----
    gcn_gather_pool<<<pgrid, 256, 0, stream>>>(rp, csr, ub, dinv, gcn_b,
                                               batch, g, N_NODES);

    // ---- head ----
    head_kernel<<<N_GRAPHS, 128, 0, stream>>>(
        g, lin1_w, lin1_b, lin2_w, lin2_b, (float*)d_out);
}

// Round 11
// 368.335 us; speedup vs baseline: 1.8402x; 1.2000x over previous
//
#include <hip/hip_runtime.h>
#include <hip/hip_bf16.h>

// Problem constants (match reference)
#define N_NODES  100000
#define N_EDGES  1600000
#define N_GRAPHS 2048
#define DIM      128   // IN_DIM == HIDDEN == 128
#define ELLW     64    // padded edges/node; deg ~ Poisson(16), max ~40

// ---- bf16 helpers (RNE encode, bit-shift decode) --------------------------
__device__ __forceinline__ unsigned short f2b(float f) {
    unsigned u = __float_as_uint(f);
    u += 0x7FFFu + ((u >> 16) & 1u);
    return (unsigned short)(u >> 16);
}
__device__ __forceinline__ float b2f(unsigned short h) {
    return __uint_as_float(((unsigned)h) << 16);
}
__device__ __forceinline__ float4 dec4(ushort4 h) {
    return make_float4(b2f(h.x), b2f(h.y), b2f(h.z), b2f(h.w));
}

// MFMA fragment types (gfx950, 16x16x32 bf16: 8 bf16 in / 4 fp32 acc)
typedef __attribute__((ext_vector_type(8))) short bfrag;
typedef __attribute__((ext_vector_type(4))) float ffrag;

// ===========================================================================
// Cast fp32 -> bf16 (8 elems/thread). Also zeroes cursor[] (covered by the
// 1.6M threads) -- replaces a hipMemsetAsync.
// ===========================================================================
__global__ __launch_bounds__(256)
void cast_bf16(const float* __restrict__ in, unsigned short* __restrict__ out,
               int* __restrict__ cursor, int n8)
{
    int i = blockIdx.x * 256 + threadIdx.x;
    if (i < N_NODES) cursor[i] = 0;
    if (i >= n8) return;
    const float4* in4 = (const float4*)in;
    float4 a = in4[i * 2 + 0];
    float4 b = in4[i * 2 + 1];
    uint4 q;
    q.x = (unsigned)f2b(a.x) | ((unsigned)f2b(a.y) << 16);
    q.y = (unsigned)f2b(a.z) | ((unsigned)f2b(a.w) << 16);
    q.z = (unsigned)f2b(b.x) | ((unsigned)f2b(b.y) << 16);
    q.w = (unsigned)f2b(b.z) | ((unsigned)f2b(b.w) << 16);
    ((uint4*)out)[i] = q;
}

// Cast + transpose all 3 weights in one launch: Wt[n][k] = bf16(W[k][n])
__global__ __launch_bounds__(256)
void cast_tr_w3(const float* __restrict__ Wa, unsigned short* __restrict__ Ta,
                const float* __restrict__ Wb, unsigned short* __restrict__ Tb,
                const float* __restrict__ Wc, unsigned short* __restrict__ Tc)
{
    int which = blockIdx.x >> 6;
    int f = (blockIdx.x & 63) * 256 + threadIdx.x;   // 0..16383
    const float* W = (which == 0) ? Wa : (which == 1) ? Wb : Wc;
    unsigned short* T = (which == 0) ? Ta : (which == 1) ? Tb : Tc;
    int k = f >> 7, n = f & 127;
    T[n * DIM + k] = f2b(W[f]);
}

// ===========================================================================
// ELL fill (replaces cnt + 3-phase scan + csr_fill):
//   pos = cursor[dst]++;  ell[dst*ELLW + pos] = src;  (cursor ends = degree)
// XCD-range-partitioned (round-4 win): range r = blockIdx&7 owns dst in
// [r*12500,(r+1)*12500) -> per-range ELL window 3.2 MB < 4 MB L2, so the 16
// stores filling each cacheline coalesce in one XCD's L2.
// Also zeroes g[] (1024 blocks x 256 = exactly N_GRAPHS*DIM).
// ===========================================================================
#define FILL_RANGES 8
#define FILL_RSIZE  (N_NODES / FILL_RANGES)   // 12500 exact

__global__ __launch_bounds__(256)
void ell_fill(const int* __restrict__ src, const int* __restrict__ dst,
              int* __restrict__ cursor, int* __restrict__ ell,
              float* __restrict__ g, int E)
{
    int gid = blockIdx.x * 256 + threadIdx.x;   // grid=1024 -> covers |g|
    g[gid] = 0.f;

    const int r = blockIdx.x & (FILL_RANGES - 1);
    const int s = blockIdx.x >> 3;
    const int nslice = gridDim.x >> 3;
    const unsigned lo = (unsigned)(r * FILL_RSIZE);
    const int stride = nslice * 256 * 4;

    for (int e0 = (s * 256 + threadIdx.x) * 4; e0 < E; e0 += stride) {
        int4 d  = *(const int4*)&dst[e0];
        int4 sv = *(const int4*)&src[e0];
        if ((unsigned)(d.x - lo) < (unsigned)FILL_RSIZE) {
            int p = atomicAdd(&cursor[d.x], 1); ell[d.x * ELLW + p] = sv.x;
        }
        if ((unsigned)(d.y - lo) < (unsigned)FILL_RSIZE) {
            int p = atomicAdd(&cursor[d.y], 1); ell[d.y * ELLW + p] = sv.y;
        }
        if ((unsigned)(d.z - lo) < (unsigned)FILL_RSIZE) {
            int p = atomicAdd(&cursor[d.z], 1); ell[d.z * ELLW + p] = sv.z;
        }
        if ((unsigned)(d.w - lo) < (unsigned)FILL_RSIZE) {
            int p = atomicAdd(&cursor[d.w], 1); ell[d.w * ELLW + p] = sv.w;
        }
    }
}

// ===========================================================================
// bf16 ELL gather -> bf16 out: Out[i] = Vb[i] + sum_{e<deg[i]} Vb[ell[i][e]]
// (fp32 accumulate). Lane 0 also writes dinv[i] = rsqrt(deg+1).
// One node per 32-lane group, ushort4 per lane, x8/x4/x1 unroll tiers.
// ===========================================================================
__global__ __launch_bounds__(256)
void ell_gather_bb(const int* __restrict__ deg, const int* __restrict__ ell,
                   const unsigned short* __restrict__ Vb,
                   unsigned short* __restrict__ Out,
                   float* __restrict__ dinv, int N)
{
    int node = blockIdx.x * 8 + (threadIdx.x >> 5);
    int lane = threadIdx.x & 31;
    if (node >= N) return;
    int dn = deg[node];
    if (lane == 0) dinv[node] = rsqrtf((float)dn + 1.0f);
    const int* row = ell + node * ELLW;
    const ushort4* V4 = (const ushort4*)Vb;
    float4 acc = dec4(V4[(size_t)node * 32 + lane]);   // self term
    int e = 0;
    for (; e + 8 <= dn; e += 8) {
        int s0 = row[e + 0], s1 = row[e + 1], s2 = row[e + 2], s3 = row[e + 3];
        int s4 = row[e + 4], s5 = row[e + 5], s6 = row[e + 6], s7 = row[e + 7];
        float4 v0 = dec4(V4[(size_t)s0 * 32 + lane]);
        float4 v1 = dec4(V4[(size_t)s1 * 32 + lane]);
        float4 v2 = dec4(V4[(size_t)s2 * 32 + lane]);
        float4 v3 = dec4(V4[(size_t)s3 * 32 + lane]);
        float4 v4 = dec4(V4[(size_t)s4 * 32 + lane]);
        float4 v5 = dec4(V4[(size_t)s5 * 32 + lane]);
        float4 v6 = dec4(V4[(size_t)s6 * 32 + lane]);
        float4 v7 = dec4(V4[(size_t)s7 * 32 + lane]);
        acc.x += (v0.x + v1.x + v2.x + v3.x) + (v4.x + v5.x + v6.x + v7.x);
        acc.y += (v0.y + v1.y + v2.y + v3.y) + (v4.y + v5.y + v6.y + v7.y);
        acc.z += (v0.z + v1.z + v2.z + v3.z) + (v4.z + v5.z + v6.z + v7.z);
        acc.w += (v0.w + v1.w + v2.w + v3.w) + (v4.w + v5.w + v6.w + v7.w);
    }
    for (; e + 4 <= dn; e += 4) {
        int s0 = row[e + 0], s1 = row[e + 1], s2 = row[e + 2], s3 = row[e + 3];
        float4 v0 = dec4(V4[(size_t)s0 * 32 + lane]);
        float4 v1 = dec4(V4[(size_t)s1 * 32 + lane]);
        float4 v2 = dec4(V4[(size_t)s2 * 32 + lane]);
        float4 v3 = dec4(V4[(size_t)s3 * 32 + lane]);
        acc.x += v0.x + v1.x + v2.x + v3.x;
        acc.y += v0.y + v1.y + v2.y + v3.y;
        acc.z += v0.z + v1.z + v2.z + v3.z;
        acc.w += v0.w + v1.w + v2.w + v3.w;
    }
    for (; e < dn; ++e) {
        int s = row[e];
        float4 v = dec4(V4[(size_t)s * 32 + lane]);
        acc.x += v.x; acc.y += v.y; acc.z += v.z; acc.w += v.w;
    }
    ushort4 o;
    o.x = f2b(acc.x); o.y = f2b(acc.y); o.z = f2b(acc.z); o.w = f2b(acc.w);
    ((ushort4*)Out)[(size_t)node * 32 + lane] = o;
}

// ===========================================================================
// Fused 3-layer MLP via MFMA 16x16x32 bf16 (fp32 accumulate), W staged in LDS
// (round-10 win). Block = 256 thr = 4 waves; 64 rows; wave w owns 16 rows
// (row-parallel). LDS: Hb 17.4K + Ws 34.8K = 52.2K -> 3 blocks/CU.
// A-frag: A[m=lane&15][k=quad*8+j]; B-frag from Ws[n][k];
// C/D: col=lane&15, row=quad*4+reg (verified layouts, m89/m120).
// ===========================================================================
#define MLP_ROWS 64
#define HBST     136

__global__ __launch_bounds__(256)
void mlp3_mfma(const unsigned short* __restrict__ Hg,
               const unsigned short* __restrict__ w1t, const float* __restrict__ b1,
               const unsigned short* __restrict__ w2t, const float* __restrict__ b2,
               const unsigned short* __restrict__ w3t, const float* __restrict__ dinv,
               unsigned short* __restrict__ ub_out, int N)
{
    __shared__ unsigned short Hb[MLP_ROWS][HBST];
    __shared__ unsigned short Ws[DIM][HBST];

    const int tid  = threadIdx.x;
    const int wave = tid >> 6;        // 0..3
    const int lane = tid & 63;
    const int row0 = blockIdx.x * MLP_ROWS;

    // ---- load H tile (coalesced uint4 = 8 bf16): 1024 x 16 B, 4/thread ----
#pragma unroll
    for (int l = 0; l < 4; ++l) {
        int f  = tid + l * 256;       // 0..1023
        int r  = f >> 4;              // 0..63
        int c8 = (f & 15) << 3;       // 0,8,...,120
        int gr = row0 + r;
        uint4 v = make_uint4(0u, 0u, 0u, 0u);
        if (gr < N) v = *(const uint4*)&Hg[(size_t)gr * DIM + c8];
        *(uint4*)&Hb[r][c8] = v;
    }

    const int m0 = wave * 16;
    const int qa = lane >> 4;         // quad 0..3
    const int la = lane & 15;

    for (int layer = 0; layer < 3; ++layer) {
        const unsigned short* __restrict__ Wt =
            (layer == 0) ? w1t : (layer == 1) ? w2t : w3t;

        // ---- stage Wt[128][128] -> Ws: 2048 uint4, 8/thread (L2-hot) ----
        __syncthreads();   // prior-layer Ws reads (and layer-0 H load) done
#pragma unroll
        for (int l = 0; l < 8; ++l) {
            int f  = tid + l * 256;   // 0..2047
            int r  = f >> 4;          // 0..127
            int c8 = (f & 15) << 3;
            *(uint4*)&Ws[r][c8] = *(const uint4*)&Wt[(size_t)r * DIM + c8];
        }
        __syncthreads();

        // A fragments for this wave's 16 rows, all K (4 chunks of 32)
        bfrag afr[4];
#pragma unroll
        for (int kc = 0; kc < 4; ++kc)
            afr[kc] = *(const bfrag*)&Hb[m0 + la][kc * 32 + qa * 8];

        if (layer < 2) {
            const float* bias = (layer == 0) ? b1 : b2;
#pragma unroll
            for (int nt = 0; nt < 8; ++nt) {
                const int n0 = nt * 16;
                ffrag acc = {0.f, 0.f, 0.f, 0.f};
#pragma unroll
                for (int kc = 0; kc < 4; ++kc) {
                    bfrag bfr = *(const bfrag*)&Ws[n0 + la][kc * 32 + qa * 8];
                    acc = __builtin_amdgcn_mfma_f32_16x16x32_bf16(afr[kc], bfr, acc, 0, 0, 0);
                }
                float bn = bias[n0 + la];
#pragma unroll
                for (int r = 0; r < 4; ++r) {
                    float v = fmaxf(acc[r] + bn, 0.f);
                    Hb[m0 + qa * 4 + r][n0 + la] = f2b(v);
                }
            }
            // wave-private rows: program order suffices before next layer
        } else {
            float dv[4];
#pragma unroll
            for (int r = 0; r < 4; ++r) {
                int gr = row0 + m0 + qa * 4 + r;
                dv[r] = (gr < N) ? dinv[gr] : 0.f;
            }
#pragma unroll
            for (int nt = 0; nt < 8; ++nt) {
                const int n0 = nt * 16;
                ffrag acc = {0.f, 0.f, 0.f, 0.f};
#pragma unroll
                for (int kc = 0; kc < 4; ++kc) {
                    bfrag bfr = *(const bfrag*)&Ws[n0 + la][kc * 32 + qa * 8];
                    acc = __builtin_amdgcn_mfma_f32_16x16x32_bf16(afr[kc], bfr, acc, 0, 0, 0);
                }
#pragma unroll
                for (int r = 0; r < 4; ++r) {
                    int gr = row0 + m0 + qa * 4 + r;
                    if (gr < N)
                        ub_out[(size_t)gr * DIM + n0 + la] = f2b(dv[r] * acc[r]);
                }
            }
        }
    }
}

// ===========================================================================
// Fused GCN gather (bf16 u, ELL) + finalize + global_add_pool:
//   h_i = relu(dinv_i * (u_i + sum u[ell]) + b);  g[batch[i]] += h_i
// ===========================================================================
#define P2_NODES 64
__global__ __launch_bounds__(256)
void gcn_gather_pool(const int* __restrict__ deg, const int* __restrict__ ell,
                     const unsigned short* __restrict__ ub,
                     const float* __restrict__ dinv,
                     const float* __restrict__ bias, const int* __restrict__ batch,
                     float* __restrict__ g, int N)
{
    const int grp  = threadIdx.x >> 5;
    const int lane = threadIdx.x & 31;
    const int n0   = blockIdx.x * P2_NODES + grp * 8;
    const ushort4* V4 = (const ushort4*)ub;

    float4 bj;
    bj.x = bias[lane * 4 + 0];
    bj.y = bias[lane * 4 + 1];
    bj.z = bias[lane * 4 + 2];
    bj.w = bias[lane * 4 + 3];

    float4 lsum = make_float4(0.f, 0.f, 0.f, 0.f);
    int prev = -1;

    for (int k = 0; k < 8; ++k) {
        int node = n0 + k;
        if (node >= N) break;
        int dn = deg[node];
        const int* row = ell + node * ELLW;
        float4 acc = dec4(V4[(size_t)node * 32 + lane]);   // self term u_i
        int e = 0;
        for (; e + 8 <= dn; e += 8) {
            int s0 = row[e + 0], s1 = row[e + 1], s2 = row[e + 2], s3 = row[e + 3];
            int s4 = row[e + 4], s5 = row[e + 5], s6 = row[e + 6], s7 = row[e + 7];
            float4 v0 = dec4(V4[(size_t)s0 * 32 + lane]);
            float4 v1 = dec4(V4[(size_t)s1 * 32 + lane]);
            float4 v2 = dec4(V4[(size_t)s2 * 32 + lane]);
            float4 v3 = dec4(V4[(size_t)s3 * 32 + lane]);
            float4 v4 = dec4(V4[(size_t)s4 * 32 + lane]);
            float4 v5 = dec4(V4[(size_t)s5 * 32 + lane]);
            float4 v6 = dec4(V4[(size_t)s6 * 32 + lane]);
            float4 v7 = dec4(V4[(size_t)s7 * 32 + lane]);
            acc.x += (v0.x + v1.x + v2.x + v3.x) + (v4.x + v5.x + v6.x + v7.x);
            acc.y += (v0.y + v1.y + v2.y + v3.y) + (v4.y + v5.y + v6.y + v7.y);
            acc.z += (v0.z + v1.z + v2.z + v3.z) + (v4.z + v5.z + v6.z + v7.z);
            acc.w += (v0.w + v1.w + v2.w + v3.w) + (v4.w + v5.w + v6.w + v7.w);
        }
        for (; e + 4 <= dn; e += 4) {
            int s0 = row[e + 0], s1 = row[e + 1], s2 = row[e + 2], s3 = row[e + 3];
            float4 v0 = dec4(V4[(size_t)s0 * 32 + lane]);
            float4 v1 = dec4(V4[(size_t)s1 * 32 + lane]);
            float4 v2 = dec4(V4[(size_t)s2 * 32 + lane]);
            float4 v3 = dec4(V4[(size_t)s3 * 32 + lane]);
            acc.x += v0.x + v1.x + v2.x + v3.x;
            acc.y += v0.y + v1.y + v2.y + v3.y;
            acc.z += v0.z + v1.z + v2.z + v3.z;
            acc.w += v0.w + v1.w + v2.w + v3.w;
        }
        for (; e < dn; ++e) {
            int s = row[e];
            float4 v = dec4(V4[(size_t)s * 32 + lane]);
            acc.x += v.x; acc.y += v.y; acc.z += v.z; acc.w += v.w;
        }
        float di = dinv[node];
        float4 h;
        h.x = fmaxf(fmaf(di, acc.x, bj.x), 0.f);
        h.y = fmaxf(fmaf(di, acc.y, bj.y), 0.f);
        h.z = fmaxf(fmaf(di, acc.z, bj.z), 0.f);
        h.w = fmaxf(fmaf(di, acc.w, bj.w), 0.f);

        int b = batch[node];
        if (b != prev) {
            if (prev >= 0) {
                float* gp = &g[(size_t)prev * DIM + lane * 4];
                atomicAdd(gp + 0, lsum.x);
                atomicAdd(gp + 1, lsum.y);
                atomicAdd(gp + 2, lsum.z);
                atomicAdd(gp + 3, lsum.w);
            }
            lsum = make_float4(0.f, 0.f, 0.f, 0.f);
            prev = b;
        }
        lsum.x += h.x; lsum.y += h.y; lsum.z += h.z; lsum.w += h.w;
    }
    if (prev >= 0) {
        float* gp = &g[(size_t)prev * DIM + lane * 4];
        atomicAdd(gp + 0, lsum.x);
        atomicAdd(gp + 1, lsum.y);
        atomicAdd(gp + 2, lsum.z);
        atomicAdd(gp + 3, lsum.w);
    }
}

// ===========================================================================
// Head: out[gid] = relu(g[gid] @ lin1_w + b1) @ lin2_w + b2
// ===========================================================================
__global__ __launch_bounds__(128)
void head_kernel(const float* __restrict__ g, const float* __restrict__ w1,
                 const float* __restrict__ b1, const float* __restrict__ w2,
                 const float* __restrict__ b2, float* __restrict__ out)
{
    __shared__ float gs[DIM];
    __shared__ float red[6];
    int gid = blockIdx.x;
    int t = threadIdx.x;

    gs[t] = g[(size_t)gid * DIM + t];
    __syncthreads();

    float acc = b1[t];
#pragma unroll
    for (int k = 0; k < DIM; ++k) acc = fmaf(gs[k], w1[k * DIM + t], acc);
    float h = fmaxf(acc, 0.f);

    float c0 = h * w2[t * 3 + 0];
    float c1 = h * w2[t * 3 + 1];
    float c2 = h * w2[t * 3 + 2];
#pragma unroll
    for (int off = 32; off >= 1; off >>= 1) {
        c0 += __shfl_down(c0, off);
        c1 += __shfl_down(c1, off);
        c2 += __shfl_down(c2, off);
    }
    int wave = t >> 6;
    if ((t & 63) == 0) {
        red[wave * 3 + 0] = c0;
        red[wave * 3 + 1] = c1;
        red[wave * 3 + 2] = c2;
    }
    __syncthreads();
    if (t == 0) {
        out[(size_t)gid * 3 + 0] = red[0] + red[3] + b2[0];
        out[(size_t)gid * 3 + 1] = red[1] + red[4] + b2[1];
        out[(size_t)gid * 3 + 2] = red[2] + red[5] + b2[2];
    }
}

// ===========================================================================
extern "C" void kernel_launch(void* const* d_in, const int* in_sizes, int n_in,
                              void* d_out, int out_size, void* d_ws, size_t ws_size,
                              hipStream_t stream)
{
    const float* x       = (const float*)d_in[0];
    const int*   eidx    = (const int*)d_in[1];
    const int*   batch   = (const int*)d_in[2];
    const float* gin_w1  = (const float*)d_in[3];
    const float* gin_b1  = (const float*)d_in[4];
    const float* gin_w2  = (const float*)d_in[5];
    const float* gin_b2  = (const float*)d_in[6];
    const float* gcn_w   = (const float*)d_in[7];
    const float* gcn_b   = (const float*)d_in[8];
    const float* lin1_w  = (const float*)d_in[9];
    const float* lin1_b  = (const float*)d_in[10];
    const float* lin2_w  = (const float*)d_in[11];
    const float* lin2_b  = (const float*)d_in[12];

    const int* src = eidx;
    const int* dst = eidx + N_EDGES;

    // workspace carve (256B aligned); total ~105 MB
    const size_t NBH = (size_t)N_NODES * DIM * sizeof(unsigned short); // 25.6 MB
    const size_t WTB = (size_t)DIM * DIM * sizeof(unsigned short);     // 32 KB
    char* base = (char*)d_ws;
    size_t off = 0;
    auto carve = [&](size_t bytes) {
        char* p = base + off;
        off = (off + bytes + 255) & ~(size_t)255;
        return p;
    };
    unsigned short* xb  = (unsigned short*)carve(NBH);  // x in bf16
    unsigned short* hb  = (unsigned short*)carve(NBH);  // gathered H in bf16
    unsigned short* ub  = (unsigned short*)carve(NBH);  // u in bf16
    unsigned short* w1t = (unsigned short*)carve(WTB);  // gin_w1^T bf16
    unsigned short* w2t = (unsigned short*)carve(WTB);
    unsigned short* w3t = (unsigned short*)carve(WTB);
    int*   cursor = (int*)  carve(N_NODES * sizeof(int));              // -> deg
    int*   ell    = (int*)  carve((size_t)N_NODES * ELLW * sizeof(int)); // 25.6MB
    float* dinv   = (float*)carve(N_NODES * sizeof(float));
    float* g      = (float*)carve((size_t)N_GRAPHS * DIM * sizeof(float));

    const int ngrid = (N_NODES + 7) / 8;
    const int mgrid = (N_NODES + MLP_ROWS - 1) / MLP_ROWS;
    const int pgrid = (N_NODES + P2_NODES - 1) / P2_NODES;

    // ---- casts (cast_bf16 also zeroes cursor) ----
    cast_bf16<<<(N_NODES * DIM / 8 + 255) / 256, 256, 0, stream>>>(
        x, xb, cursor, N_NODES * DIM / 8);
    cast_tr_w3<<<3 * 64, 256, 0, stream>>>(gin_w1, w1t, gin_w2, w2t, gcn_w, w3t);

    // ---- ELL build (also zeroes g); cursor ends as degree ----
    ell_fill<<<FILL_RANGES * 128, 256, 0, stream>>>(src, dst, cursor, ell,
                                                    g, N_EDGES);

    // ---- GIN gather (bf16 in/out, fp32 acc); also writes dinv ----
    ell_gather_bb<<<ngrid, 256, 0, stream>>>(cursor, ell, xb, hb, dinv, N_NODES);

    // ---- fused 3-layer MLP via MFMA (W staged in LDS) -> u (bf16) ----
    mlp3_mfma<<<mgrid, 256, 0, stream>>>(hb, w1t, gin_b1, w2t, gin_b2,
                                         w3t, dinv, ub, N_NODES);

    // ---- fused GCN gather (bf16) + finalize + pool -> g ----
    gcn_gather_pool<<<pgrid, 256, 0, stream>>>(cursor, ell, ub, dinv, gcn_b,
                                               batch, g, N_NODES);

    // ---- head ----
    head_kernel<<<N_GRAPHS, 128, 0, stream>>>(
        g, lin1_w, lin1_b, lin2_w, lin2_b, (float*)d_out);
}